// Round 1
// baseline (1126.696 us; speedup 1.0000x reference)
//
#include <hip/hip_runtime.h>

typedef unsigned short u16;
typedef unsigned int   u32;

using short8  = __attribute__((ext_vector_type(8))) short;
using floatx4 = __attribute__((ext_vector_type(4))) float;

// ---------- constants ----------
#define Bb   16
#define Hh   56
#define Ww   56
#define Cc   512
#define NHh  16
#define HDd  32
#define HIDh 2048
#define Ll   (Hh*Ww)          // 3136
#define Mm   (Bb*Ll)          // 50176
#define SCALE 0.17677669529663687f
#define CSTR2 264             // epilogue C-stage row stride (u16)

// ---------- helpers ----------
__device__ __forceinline__ u16 f2bf(float f) {
  union { float f; u32 u; } v; v.f = f;
  u32 r = (v.u + 0x7fffu + ((v.u >> 16) & 1u)) >> 16;
  return (u16)r;
}
__device__ __forceinline__ float bf2f(u16 u) {
  union { u32 u; float f; } v; v.u = ((u32)u) << 16; return v.f;
}
__device__ __forceinline__ float bf2f_lo(u32 u) {
  union { u32 u; float f; } v; v.u = u << 16; return v.f;
}
__device__ __forceinline__ float bf2f_hi(u32 u) {
  union { u32 u; float f; } v; v.u = u & 0xffff0000u; return v.f;
}
__device__ __forceinline__ float gelu_f(float x) {
  return 0.5f * x * (1.f + erff(x * 0.70710678118654752f));
}
__device__ __forceinline__ void gld_lds16(const u16* g, u16* l) {
  __builtin_amdgcn_global_load_lds(
      (__attribute__((address_space(1))) void*)(void*)g,
      (__attribute__((address_space(3))) void*)(void*)l,
      16, 0, 0);
}

// ---------- weight convert+transpose: Wt[n][k] = bf16(W[k][n]) ----------
__global__ void wcvt_k(const float* __restrict__ W, u16* __restrict__ Wt,
                       int K, int N) {
  int idx = blockIdx.x * 256 + threadIdx.x;     // over N*K
  int n = idx / K;
  int k = idx - n * K;
  Wt[idx] = f2bf(W[(size_t)k * N + n]);
}

// ---------- concat 3 bias vectors (512 each) ----------
__global__ void bcat_k(const float* __restrict__ a, const float* __restrict__ b,
                       const float* __restrict__ c, float* __restrict__ o) {
  int i = blockIdx.x * 256 + threadIdx.x;   // 0..1535
  float v = (i < 512) ? a[i] : (i < 1024) ? b[i - 512] : c[i - 1024];
  o[i] = v;
}

// ---------- layernorm fp32 in -> bf16 out, one wave per row ----------
__global__ __launch_bounds__(256)
void ln_k(const float* __restrict__ x, const float* __restrict__ g,
          const float* __restrict__ b, u16* __restrict__ out) {
  const int row  = blockIdx.x * 4 + (threadIdx.x >> 6);
  const int lane = threadIdx.x & 63;
  const float* xr = x + (size_t)row * Cc + lane * 8;
  float4 v0 = *(const float4*)xr;
  float4 v1 = *(const float4*)(xr + 4);
  float s  = v0.x+v0.y+v0.z+v0.w + v1.x+v1.y+v1.z+v1.w;
  float s2 = v0.x*v0.x+v0.y*v0.y+v0.z*v0.z+v0.w*v0.w
           + v1.x*v1.x+v1.y*v1.y+v1.z*v1.z+v1.w*v1.w;
  #pragma unroll
  for (int off = 32; off >= 1; off >>= 1) {
    s  += __shfl_xor(s,  off);
    s2 += __shfl_xor(s2, off);
  }
  float mu  = s  * (1.f/512.f);
  float var = s2 * (1.f/512.f) - mu*mu;
  float rs  = rsqrtf(var + 1e-5f);
  float4 ga = *(const float4*)(g + lane*8);
  float4 gb = *(const float4*)(g + lane*8 + 4);
  float4 ba = *(const float4*)(b + lane*8);
  float4 bb = *(const float4*)(b + lane*8 + 4);
  float o0 = (v0.x-mu)*rs*ga.x + ba.x;
  float o1 = (v0.y-mu)*rs*ga.y + ba.y;
  float o2 = (v0.z-mu)*rs*ga.z + ba.z;
  float o3 = (v0.w-mu)*rs*ga.w + ba.w;
  float o4 = (v1.x-mu)*rs*gb.x + bb.x;
  float o5 = (v1.y-mu)*rs*gb.y + bb.y;
  float o6 = (v1.z-mu)*rs*gb.z + bb.z;
  float o7 = (v1.w-mu)*rs*gb.w + bb.w;
  u32 w0 = (u32)f2bf(o0) | ((u32)f2bf(o1) << 16);
  u32 w1 = (u32)f2bf(o2) | ((u32)f2bf(o3) << 16);
  u32 w2 = (u32)f2bf(o4) | ((u32)f2bf(o5) << 16);
  u32 w3 = (u32)f2bf(o6) | ((u32)f2bf(o7) << 16);
  *(uint4*)(out + (size_t)row * Cc + lane * 8) = make_uint4(w0, w1, w2, w3);
}

// ---------- layernorm bf16 in -> bf16 out ----------
__global__ __launch_bounds__(256)
void ln_bf_k(const u16* __restrict__ x, const float* __restrict__ g,
             const float* __restrict__ b, u16* __restrict__ out) {
  const int row  = blockIdx.x * 4 + (threadIdx.x >> 6);
  const int lane = threadIdx.x & 63;
  uint4 xv = *(const uint4*)(x + (size_t)row * Cc + lane * 8);
  float v[8];
  v[0]=bf2f_lo(xv.x); v[1]=bf2f_hi(xv.x); v[2]=bf2f_lo(xv.y); v[3]=bf2f_hi(xv.y);
  v[4]=bf2f_lo(xv.z); v[5]=bf2f_hi(xv.z); v[6]=bf2f_lo(xv.w); v[7]=bf2f_hi(xv.w);
  float s = 0.f, s2 = 0.f;
  #pragma unroll
  for (int i = 0; i < 8; i++) { s += v[i]; s2 += v[i]*v[i]; }
  #pragma unroll
  for (int off = 32; off >= 1; off >>= 1) {
    s  += __shfl_xor(s,  off);
    s2 += __shfl_xor(s2, off);
  }
  float mu  = s  * (1.f/512.f);
  float var = s2 * (1.f/512.f) - mu*mu;
  float rs  = rsqrtf(var + 1e-5f);
  float4 ga = *(const float4*)(g + lane*8);
  float4 gb = *(const float4*)(g + lane*8 + 4);
  float4 ba = *(const float4*)(b + lane*8);
  float4 bb = *(const float4*)(b + lane*8 + 4);
  float o[8];
  o[0]=(v[0]-mu)*rs*ga.x+ba.x; o[1]=(v[1]-mu)*rs*ga.y+ba.y;
  o[2]=(v[2]-mu)*rs*ga.z+ba.z; o[3]=(v[3]-mu)*rs*ga.w+ba.w;
  o[4]=(v[4]-mu)*rs*gb.x+bb.x; o[5]=(v[5]-mu)*rs*gb.y+bb.y;
  o[6]=(v[6]-mu)*rs*gb.z+bb.z; o[7]=(v[7]-mu)*rs*gb.w+bb.w;
  u32 w0 = (u32)f2bf(o[0]) | ((u32)f2bf(o[1]) << 16);
  u32 w1 = (u32)f2bf(o[2]) | ((u32)f2bf(o[3]) << 16);
  u32 w2 = (u32)f2bf(o[4]) | ((u32)f2bf(o[5]) << 16);
  u32 w3 = (u32)f2bf(o[6]) | ((u32)f2bf(o[7]) << 16);
  *(uint4*)(out + (size_t)row * Cc + lane * 8) = make_uint4(w0, w1, w2, w3);
}

// ---------- GEMM: out[M,N] = A[M,K](bf16) @ Bt[N,K](bf16)^T + bias ----------
// 256x256 tile, BK=64, 8 waves (4M x 2N), 512 threads, 128 KiB LDS.
// 8-phase-per-2-K-tiles schedule (T2+T3+T4+T5):
//   - LDS st_16x32 XOR swizzle; global source pre-inverse-swizzled so
//     global_load_lds stays linear (both-sides-or-neither).
//   - per phase: 12 ds_read_b128 || 2 global_load_lds || s_barrier ||
//     lgkmcnt(0)+sched_barrier || setprio(1) 16 MFMA setprio(0) || s_barrier
//   - counted vmcnt(4) at ph0 and ph3 (never 0 mid-loop); tail tiles use
//     vmcnt(2)/vmcnt(0) because skipped stages reduce outstanding counts.
// Staging choreography (tile t, buf p=t&1):
//   ph0: A q0,q1(t+1)->buf 1-p   ph1: A q2,q3(t+1)->buf 1-p
//   ph2: B q1,q3(t+1)->buf 1-p   ph3: B q0,q2(t+2)->buf p (freed after ph2)
// MODE 0: -> bf16   MODE 1: gelu -> bf16   MODE 2: +res(fp32) -> bf16
// MODE 3: +res(bf16) -> fp32 (direct full-line stores)
template<int MODE>
__global__ __launch_bounds__(512, 2)
void gemm_bt(const u16* __restrict__ A, const u16* __restrict__ Bt,
             const float* __restrict__ bias, const void* __restrict__ res,
             void* __restrict__ outp, int M, int N, int K, int nbn) {
  (void)M;
  __shared__ __align__(16) u16 smem[65536];   // 128 KiB: 2 x (A 32K + B 32K)

  // ---- bijective XCD swizzle (m204), nt fastest for A-panel L2 reuse ----
  const int nwg = gridDim.x;
  const int bq = nwg >> 3, brr = nwg & 7;
  const int xcd = blockIdx.x & 7, bi = blockIdx.x >> 3;
  const int wg = (xcd < brr ? xcd * (bq + 1) : brr * (bq + 1) + (xcd - brr) * bq) + bi;
  const int mt = wg / nbn;
  const int nt = wg - mt * nbn;
  const int m0 = mt << 8;
  const int n0 = nt << 8;

  const int tid  = threadIdx.x;
  const int lane = tid & 63;
  const int wave = tid >> 6;
  const int wm4  = wave >> 1;          // 0..3  M quarter (64 rows)
  const int wn2  = wave & 1;           // 0..1  N half (128 cols)
  const int quad = lane >> 4;
  const int l16  = lane & 15;
  const int nT   = K >> 6;             // K-tiles of 64

  // staging source coords: inverse of the st_16x32 swizzle (u16 units).
  // physical u16 off within an 8KB quarter = tid*8; logical = phys ^ bit-swap
  int lu = tid << 3;
  lu ^= ((lu >> 8) & 1) << 4;
  const int sr = ((lu >> 10) << 4) | ((lu >> 5) & 15);   // row 0..63
  const int sc = (((lu >> 9) & 1) << 5) | (lu & 31);     // col 0..63 (x8 aligned)

  // swizzled ds_read lane offset within a (quarter, rb, ks) 1KB block
  const int lrow = ((l16 << 5) | (quad << 3)) ^ ((l16 & 8) << 1);

  const u16* Ag = A  + (size_t)(m0 + sr) * K + sc;
  const u16* Bg = Bt + (size_t)(n0 + sr) * K + sc;

#define STAGE_A(kt, q, buf) gld_lds16(Ag + (size_t)((q) << 6) * K + ((kt) << 6), \
                                      &smem[((buf) << 15) + ((q) << 12) + (wave << 9)])
#define STAGE_B(kt, q, buf) gld_lds16(Bg + (size_t)((q) << 6) * K + ((kt) << 6), \
                                      &smem[((buf) << 15) + 16384 + ((q) << 12) + (wave << 9)])

  floatx4 acc[4][8];
  #pragma unroll
  for (int i = 0; i < 4; i++)
    #pragma unroll
    for (int j = 0; j < 8; j++) acc[i][j] = (floatx4)0.f;

  // ---- prologue: tile0 (A q0-3, B even, B odd), then tile1 B even ----
  STAGE_A(0, 0, 0); STAGE_A(0, 1, 0); STAGE_A(0, 2, 0); STAGE_A(0, 3, 0);
  STAGE_B(0, 0, 0); STAGE_B(0, 2, 0);
  STAGE_B(0, 1, 0); STAGE_B(0, 3, 0);
  if (nT > 1) { STAGE_B(1, 0, 1); STAGE_B(1, 2, 1); }
  asm volatile("s_waitcnt vmcnt(4)" ::: "memory");   // A(0)+Beven(0) landed
  __builtin_amdgcn_s_barrier();

  for (int t = 0; t < nT; ++t) {
    const int cbuf  = t & 1;
    const int abase = (cbuf << 15) + (wm4 << 12);
    const int bbase = (cbuf << 15) + 16384 + (wn2 << 13);
    const bool s1 = (t + 1) < nT;
    const bool s2 = (t + 2) < nT;
    #pragma unroll
    for (int p = 0; p < 4; ++p) {
      // --- ds_read this phase's operand subtiles (12 x ds_read_b128) ---
      short8 af[2][2], bf[4][2];
      #pragma unroll
      for (int m = 0; m < 2; ++m)
        #pragma unroll
        for (int ks = 0; ks < 2; ++ks)
          af[m][ks] = *(const short8*)&smem[abase + (((p >> 1) * 2 + m) << 10)
                                            + (ks << 9) + lrow];
      #pragma unroll
      for (int n = 0; n < 4; ++n)
        #pragma unroll
        for (int ks = 0; ks < 2; ++ks)
          bf[n][ks] = *(const short8*)&smem[bbase + ((p & 1) << 12) + (n << 10)
                                            + (ks << 9) + lrow];
      // --- stage one half-tile (2 x global_load_lds) + counted vmcnt ---
      if (p == 0) {
        if (s1) {
          STAGE_A(t + 1, 0, cbuf ^ 1); STAGE_A(t + 1, 1, cbuf ^ 1);
          asm volatile("s_waitcnt vmcnt(4)" ::: "memory");   // Bodd(t) landed
        } else {
          asm volatile("s_waitcnt vmcnt(0)" ::: "memory");   // last tile: drain
        }
      } else if (p == 1) {
        if (s1) { STAGE_A(t + 1, 2, cbuf ^ 1); STAGE_A(t + 1, 3, cbuf ^ 1); }
      } else if (p == 2) {
        if (s1) { STAGE_B(t + 1, 1, cbuf ^ 1); STAGE_B(t + 1, 3, cbuf ^ 1); }
      } else {
        if (s2) {
          STAGE_B(t + 2, 0, cbuf); STAGE_B(t + 2, 2, cbuf);  // over Beven(t), freed ph2
          asm volatile("s_waitcnt vmcnt(4)" ::: "memory");   // A(t+1)+Beven(t+1) landed
        } else if (s1) {
          asm volatile("s_waitcnt vmcnt(2)" ::: "memory");   // tail: fewer in flight
        }
      }
      __builtin_amdgcn_s_barrier();
      asm volatile("s_waitcnt lgkmcnt(0)" ::: "memory");
      __builtin_amdgcn_sched_barrier(0);
      __builtin_amdgcn_s_setprio(1);
      #pragma unroll
      for (int n = 0; n < 4; ++n)
        #pragma unroll
        for (int m = 0; m < 2; ++m)
          #pragma unroll
          for (int ks = 0; ks < 2; ++ks)
            acc[(p >> 1) * 2 + m][(p & 1) * 4 + n] =
                __builtin_amdgcn_mfma_f32_16x16x32_bf16(
                    af[m][ks], bf[n][ks],
                    acc[(p >> 1) * 2 + m][(p & 1) * 4 + n], 0, 0, 0);
      __builtin_amdgcn_s_setprio(0);
      __builtin_amdgcn_s_barrier();
    }
  }
#undef STAGE_A
#undef STAGE_B

  if (MODE == 3) {
    // fp32 direct stores: 16 lanes x 4B consecutive = full 64B lines.
    const int mrow = m0 + (wm4 << 6) + (quad << 2);
    const int ncol = n0 + (wn2 << 7) + l16;
    #pragma unroll
    for (int ni = 0; ni < 8; ++ni) {
      const int n = ncol + ni * 16;
      const float bv = bias[n];
      #pragma unroll
      for (int mi = 0; mi < 4; ++mi)
        #pragma unroll
        for (int r = 0; r < 4; ++r) {
          const size_t idx = (size_t)(mrow + mi * 16 + r) * N + n;
          ((float*)outp)[idx] = acc[mi][ni][r] + bv + bf2f(((const u16*)res)[idx]);
        }
    }
  } else {
    // stage bf16 C in two 128-row halves through LDS, 16B/lane writeout
    #pragma unroll
    for (int h = 0; h < 2; ++h) {
      __syncthreads();
      if ((wm4 >> 1) == h) {
        const int rb0 = ((wm4 & 1) << 6) + (quad << 2);
        #pragma unroll
        for (int ni = 0; ni < 8; ++ni) {
          const int col = (wn2 << 7) + ni * 16 + l16;
          const float bv = bias[n0 + col];
          #pragma unroll
          for (int mi = 0; mi < 4; ++mi)
            #pragma unroll
            for (int r = 0; r < 4; ++r) {
              float v = acc[mi][ni][r] + bv;
              if (MODE == 1) v = gelu_f(v);
              smem[(rb0 + mi * 16 + r) * CSTR2 + col] = f2bf(v);
            }
        }
      }
      __syncthreads();
      const int trow = tid >> 5;            // 0..15
      const int tcol = (tid & 31) << 3;     // u16 col
      #pragma unroll
      for (int it = 0; it < 8; ++it) {
        const int row = it * 16 + trow;
        uint4 w = *(const uint4*)&smem[row * CSTR2 + tcol];
        const size_t gi = (size_t)(m0 + (h << 7) + row) * N + n0 + tcol;
        if (MODE == 2) {
          const float* rp = (const float*)res + gi;
          float4 ra  = *(const float4*)rp;
          float4 rb2 = *(const float4*)(rp + 4);
          u32 w0 = (u32)f2bf(bf2f_lo(w.x) + ra.x)  | ((u32)f2bf(bf2f_hi(w.x) + ra.y)  << 16);
          u32 w1 = (u32)f2bf(bf2f_lo(w.y) + ra.z)  | ((u32)f2bf(bf2f_hi(w.y) + ra.w)  << 16);
          u32 w2 = (u32)f2bf(bf2f_lo(w.z) + rb2.x) | ((u32)f2bf(bf2f_hi(w.z) + rb2.y) << 16);
          u32 w3 = (u32)f2bf(bf2f_lo(w.w) + rb2.z) | ((u32)f2bf(bf2f_hi(w.w) + rb2.w) << 16);
          *(uint4*)((u16*)outp + gi) = make_uint4(w0, w1, w2, w3);
        } else {
          *(uint4*)((u16*)outp + gi) = w;
        }
      }
    }
  }
}

// ---------- windowed attention, one wave per (window, head) ----------
__global__ __launch_bounds__(64)
void attn_k(const u16* __restrict__ QKV, const float* __restrict__ rel,
            u16* __restrict__ O) {
  const int win  = blockIdx.x;          // 0..1023
  const int head = blockIdx.y;          // 0..15
  const int b    = win >> 6;
  const int wh   = (win >> 3) & 7;
  const int ww   = win & 7;
  const int lane = threadIdx.x;

  __shared__ float Ks[49][36];
  __shared__ float Vs[49][36];

  const bool active = lane < 49;
  size_t rowq = 0, rowo = 0;
  float q[32];
  if (active) {
    const int i = lane / 7, j = lane - 7 * (lane / 7);
    const int l = (wh * 7 + i) * Ww + ww * 7 + j;
    const size_t gr = (size_t)(b * Ll + l);
    rowq = gr * 1536 + head * HDd;
    rowo = gr * 512  + head * HDd;
    const uint4* qp = (const uint4*)(QKV + rowq);
    const uint4* kp = (const uint4*)(QKV + rowq + 512);
    const uint4* vp = (const uint4*)(QKV + rowq + 1024);
    #pragma unroll
    for (int c = 0; c < 4; c++) {
      uint4 qv = qp[c], kv = kp[c], vv = vp[c];
      q[c*8+0] = bf2f_lo(qv.x) * SCALE; q[c*8+1] = bf2f_hi(qv.x) * SCALE;
      q[c*8+2] = bf2f_lo(qv.y) * SCALE; q[c*8+3] = bf2f_hi(qv.y) * SCALE;
      q[c*8+4] = bf2f_lo(qv.z) * SCALE; q[c*8+5] = bf2f_hi(qv.z) * SCALE;
      q[c*8+6] = bf2f_lo(qv.w) * SCALE; q[c*8+7] = bf2f_hi(qv.w) * SCALE;
      *(float4*)&Ks[lane][c*8]   = make_float4(bf2f_lo(kv.x), bf2f_hi(kv.x),
                                               bf2f_lo(kv.y), bf2f_hi(kv.y));
      *(float4*)&Ks[lane][c*8+4] = make_float4(bf2f_lo(kv.z), bf2f_hi(kv.z),
                                               bf2f_lo(kv.w), bf2f_hi(kv.w));
      *(float4*)&Vs[lane][c*8]   = make_float4(bf2f_lo(vv.x), bf2f_hi(vv.x),
                                               bf2f_lo(vv.y), bf2f_hi(vv.y));
      *(float4*)&Vs[lane][c*8+4] = make_float4(bf2f_lo(vv.z), bf2f_hi(vv.z),
                                               bf2f_lo(vv.w), bf2f_hi(vv.w));
    }
  }
  __syncthreads();
  if (!active) return;

  const float* rb = rel + ((size_t)head * 49 + lane) * 49;
  float s[49];
  float mx = -1e30f;
  #pragma unroll
  for (int m = 0; m < 49; m++) {
    float d = 0.f;
    #pragma unroll
    for (int c = 0; c < 8; c++) {
      float4 kk = *(const float4*)&Ks[m][c*4];
      d += q[c*4+0]*kk.x + q[c*4+1]*kk.y + q[c*4+2]*kk.z + q[c*4+3]*kk.w;
    }
    d += rb[m];
    s[m] = d;
    mx = fmaxf(mx, d);
  }
  float sum = 0.f;
  #pragma unroll
  for (int m = 0; m < 49; m++) { float e = __expf(s[m] - mx); s[m] = e; sum += e; }
  const float inv = 1.f / sum;

  float acc[32];
  #pragma unroll
  for (int d = 0; d < 32; d++) acc[d] = 0.f;
  #pragma unroll
  for (int m = 0; m < 49; m++) {
    const float p = s[m];
    #pragma unroll
    for (int c = 0; c < 8; c++) {
      float4 vv = *(const float4*)&Vs[m][c*4];
      acc[c*4+0] += p*vv.x; acc[c*4+1] += p*vv.y;
      acc[c*4+2] += p*vv.z; acc[c*4+3] += p*vv.w;
    }
  }
  uint4* op = (uint4*)(O + rowo);
  #pragma unroll
  for (int c = 0; c < 4; c++) {
    u32 w0 = (u32)f2bf(acc[c*8+0]*inv) | ((u32)f2bf(acc[c*8+1]*inv) << 16);
    u32 w1 = (u32)f2bf(acc[c*8+2]*inv) | ((u32)f2bf(acc[c*8+3]*inv) << 16);
    u32 w2 = (u32)f2bf(acc[c*8+4]*inv) | ((u32)f2bf(acc[c*8+5]*inv) << 16);
    u32 w3 = (u32)f2bf(acc[c*8+6]*inv) | ((u32)f2bf(acc[c*8+7]*inv) << 16);
    op[c] = make_uint4(w0, w1, w2, w3);
  }
}

// ---------- launch ----------
extern "C" void kernel_launch(void* const* d_in, const int* in_sizes, int n_in,
                              void* d_out, int out_size, void* d_ws, size_t ws_size,
                              hipStream_t stream) {
  (void)in_sizes; (void)n_in; (void)out_size; (void)ws_size;
  const float* x    = (const float*)d_in[0];
  const float* Wq   = (const float*)d_in[1];
  const float* bq   = (const float*)d_in[2];
  const float* Wk   = (const float*)d_in[3];
  const float* bk   = (const float*)d_in[4];
  const float* Wv   = (const float*)d_in[5];
  const float* bv   = (const float*)d_in[6];
  const float* Wp   = (const float*)d_in[7];
  const float* bp   = (const float*)d_in[8];
  const float* rel  = (const float*)d_in[9];
  const float* g1   = (const float*)d_in[10];
  const float* b1   = (const float*)d_in[11];
  const float* g2   = (const float*)d_in[12];
  const float* b2   = (const float*)d_in[13];
  const float* W1   = (const float*)d_in[14];
  const float* bfc1 = (const float*)d_in[15];
  const float* W2   = (const float*)d_in[16];
  const float* bfc2 = (const float*)d_in[17];
  float* out = (float*)d_out;

  // workspace layout (u16 units)
  u16* wQKV = (u16*)d_ws;                          // 1536*512
  u16* wWp  = wQKV + (size_t)1536*512;             // 512*512
  u16* wW1  = wWp  + (size_t)512*512;              // 2048*512
  u16* wW2  = wW1  + (size_t)2048*512;             // 512*2048
  float* bqkv = (float*)(wW2 + (size_t)512*2048);  // 1536 fp32
  u16* hbuf = (u16*)(bqkv + 1536);                 // M*512 (LN1 out; later LN2 out)
  u16* QKVb = hbuf + (size_t)Mm * Cc;              // M*1536 (later: MLP hidden part)
  u16* Obuf = QKVb + (size_t)Mm * 1536;            // M*512
  u16* x2bf = Obuf + (size_t)Mm * Cc;              // M*512 bf16 residual
  u16* hid  = QKVb;                                // M*2048 overlays QKVb+Obuf
  u16* h2   = hbuf;

  // weights -> bf16 transposed (QKV fused into 1536 rows)
  wcvt_k<<<(512*512)/256,  256, 0, stream>>>(Wq, wQKV,              512, 512);
  wcvt_k<<<(512*512)/256,  256, 0, stream>>>(Wk, wQKV + 512*512,    512, 512);
  wcvt_k<<<(512*512)/256,  256, 0, stream>>>(Wv, wQKV + 2*512*512,  512, 512);
  wcvt_k<<<(512*512)/256,  256, 0, stream>>>(Wp, wWp, 512, 512);
  wcvt_k<<<(512*2048)/256, 256, 0, stream>>>(W1, wW1, 512, 2048);
  wcvt_k<<<(512*2048)/256, 256, 0, stream>>>(W2, wW2, 2048, 512);
  bcat_k<<<6, 256, 0, stream>>>(bq, bk, bv, bqkv);

  // LN1
  ln_k<<<Mm/4, 256, 0, stream>>>(x, g1, b1, hbuf);

  // fused QKV projection: (M,1536) = 196 x 6 tiles of 256
  gemm_bt<0><<<196*6, 512, 0, stream>>>(hbuf, wQKV, bqkv, nullptr, QKVb,
                                        Mm, 1536, 512, 6);

  // attention
  attn_k<<<dim3(1024, 16), 64, 0, stream>>>(QKVb, rel, Obuf);

  // proj + residual(x fp32) -> x2 bf16
  gemm_bt<2><<<196*2, 512, 0, stream>>>(Obuf, wWp, bp, x, x2bf,
                                        Mm, 512, 512, 2);

  // LN2 (bf16 in)
  ln_bf_k<<<Mm/4, 256, 0, stream>>>(x2bf, g2, b2, h2);

  // MLP
  gemm_bt<1><<<196*8, 512, 0, stream>>>(h2, wW1, bfc1, nullptr, hid,
                                        Mm, 2048, 512, 8);
  gemm_bt<3><<<196*2, 512, 0, stream>>>(hid, wW2, bfc2, x2bf, out,
                                        Mm, 512, 2048, 2);
}

// Round 2
// 1088.230 us; speedup vs baseline: 1.0353x; 1.0353x over previous
//
#include <hip/hip_runtime.h>

typedef unsigned short u16;
typedef unsigned int   u32;

using short8  = __attribute__((ext_vector_type(8))) short;
using floatx4 = __attribute__((ext_vector_type(4))) float;

// ---------- constants ----------
#define Bb   16
#define Hh   56
#define Ww   56
#define Cc   512
#define NHh  16
#define HDd  32
#define HIDh 2048
#define Ll   (Hh*Ww)          // 3136
#define Mm   (Bb*Ll)          // 50176
#define SCALE 0.17677669529663687f
#define CSTR2 264             // epilogue C-stage row stride (u16)

// ---------- helpers ----------
__device__ __forceinline__ u16 f2bf(float f) {
  union { float f; u32 u; } v; v.f = f;
  u32 r = (v.u + 0x7fffu + ((v.u >> 16) & 1u)) >> 16;
  return (u16)r;
}
__device__ __forceinline__ float bf2f(u16 u) {
  union { u32 u; float f; } v; v.u = ((u32)u) << 16; return v.f;
}
__device__ __forceinline__ float bf2f_lo(u32 u) {
  union { u32 u; float f; } v; v.u = u << 16; return v.f;
}
__device__ __forceinline__ float bf2f_hi(u32 u) {
  union { u32 u; float f; } v; v.u = u & 0xffff0000u; return v.f;
}
__device__ __forceinline__ float gelu_f(float x) {
  return 0.5f * x * (1.f + erff(x * 0.70710678118654752f));
}
__device__ __forceinline__ void gld_lds16(const u16* g, u16* l) {
  __builtin_amdgcn_global_load_lds(
      (__attribute__((address_space(1))) void*)(void*)g,
      (__attribute__((address_space(3))) void*)(void*)l,
      16, 0, 0);
}

// ---------- weight convert+transpose: Wt[n][k] = bf16(W[k][n]) ----------
__global__ void wcvt_k(const float* __restrict__ W, u16* __restrict__ Wt,
                       int K, int N) {
  int idx = blockIdx.x * 256 + threadIdx.x;     // over N*K
  int n = idx / K;
  int k = idx - n * K;
  Wt[idx] = f2bf(W[(size_t)k * N + n]);
}

// ---------- concat 3 bias vectors (512 each) ----------
__global__ void bcat_k(const float* __restrict__ a, const float* __restrict__ b,
                       const float* __restrict__ c, float* __restrict__ o) {
  int i = blockIdx.x * 256 + threadIdx.x;   // 0..1535
  float v = (i < 512) ? a[i] : (i < 1024) ? b[i - 512] : c[i - 1024];
  o[i] = v;
}

// ---------- layernorm fp32 in -> bf16 out, one wave per row ----------
__global__ __launch_bounds__(256)
void ln_k(const float* __restrict__ x, const float* __restrict__ g,
          const float* __restrict__ b, u16* __restrict__ out) {
  const int row  = blockIdx.x * 4 + (threadIdx.x >> 6);
  const int lane = threadIdx.x & 63;
  const float* xr = x + (size_t)row * Cc + lane * 8;
  float4 v0 = *(const float4*)xr;
  float4 v1 = *(const float4*)(xr + 4);
  float s  = v0.x+v0.y+v0.z+v0.w + v1.x+v1.y+v1.z+v1.w;
  float s2 = v0.x*v0.x+v0.y*v0.y+v0.z*v0.z+v0.w*v0.w
           + v1.x*v1.x+v1.y*v1.y+v1.z*v1.z+v1.w*v1.w;
  #pragma unroll
  for (int off = 32; off >= 1; off >>= 1) {
    s  += __shfl_xor(s,  off);
    s2 += __shfl_xor(s2, off);
  }
  float mu  = s  * (1.f/512.f);
  float var = s2 * (1.f/512.f) - mu*mu;
  float rs  = rsqrtf(var + 1e-5f);
  float4 ga = *(const float4*)(g + lane*8);
  float4 gb = *(const float4*)(g + lane*8 + 4);
  float4 ba = *(const float4*)(b + lane*8);
  float4 bb = *(const float4*)(b + lane*8 + 4);
  float o0 = (v0.x-mu)*rs*ga.x + ba.x;
  float o1 = (v0.y-mu)*rs*ga.y + ba.y;
  float o2 = (v0.z-mu)*rs*ga.z + ba.z;
  float o3 = (v0.w-mu)*rs*ga.w + ba.w;
  float o4 = (v1.x-mu)*rs*gb.x + bb.x;
  float o5 = (v1.y-mu)*rs*gb.y + bb.y;
  float o6 = (v1.z-mu)*rs*gb.z + bb.z;
  float o7 = (v1.w-mu)*rs*gb.w + bb.w;
  u32 w0 = (u32)f2bf(o0) | ((u32)f2bf(o1) << 16);
  u32 w1 = (u32)f2bf(o2) | ((u32)f2bf(o3) << 16);
  u32 w2 = (u32)f2bf(o4) | ((u32)f2bf(o5) << 16);
  u32 w3 = (u32)f2bf(o6) | ((u32)f2bf(o7) << 16);
  *(uint4*)(out + (size_t)row * Cc + lane * 8) = make_uint4(w0, w1, w2, w3);
}

// ---------- layernorm bf16 in -> bf16 out ----------
__global__ __launch_bounds__(256)
void ln_bf_k(const u16* __restrict__ x, const float* __restrict__ g,
             const float* __restrict__ b, u16* __restrict__ out) {
  const int row  = blockIdx.x * 4 + (threadIdx.x >> 6);
  const int lane = threadIdx.x & 63;
  uint4 xv = *(const uint4*)(x + (size_t)row * Cc + lane * 8);
  float v[8];
  v[0]=bf2f_lo(xv.x); v[1]=bf2f_hi(xv.x); v[2]=bf2f_lo(xv.y); v[3]=bf2f_hi(xv.y);
  v[4]=bf2f_lo(xv.z); v[5]=bf2f_hi(xv.z); v[6]=bf2f_lo(xv.w); v[7]=bf2f_hi(xv.w);
  float s = 0.f, s2 = 0.f;
  #pragma unroll
  for (int i = 0; i < 8; i++) { s += v[i]; s2 += v[i]*v[i]; }
  #pragma unroll
  for (int off = 32; off >= 1; off >>= 1) {
    s  += __shfl_xor(s,  off);
    s2 += __shfl_xor(s2, off);
  }
  float mu  = s  * (1.f/512.f);
  float var = s2 * (1.f/512.f) - mu*mu;
  float rs  = rsqrtf(var + 1e-5f);
  float4 ga = *(const float4*)(g + lane*8);
  float4 gb = *(const float4*)(g + lane*8 + 4);
  float4 ba = *(const float4*)(b + lane*8);
  float4 bb = *(const float4*)(b + lane*8 + 4);
  float o[8];
  o[0]=(v[0]-mu)*rs*ga.x+ba.x; o[1]=(v[1]-mu)*rs*ga.y+ba.y;
  o[2]=(v[2]-mu)*rs*ga.z+ba.z; o[3]=(v[3]-mu)*rs*ga.w+ba.w;
  o[4]=(v[4]-mu)*rs*gb.x+bb.x; o[5]=(v[5]-mu)*rs*gb.y+bb.y;
  o[6]=(v[6]-mu)*rs*gb.z+bb.z; o[7]=(v[7]-mu)*rs*gb.w+bb.w;
  u32 w0 = (u32)f2bf(o[0]) | ((u32)f2bf(o[1]) << 16);
  u32 w1 = (u32)f2bf(o[2]) | ((u32)f2bf(o[3]) << 16);
  u32 w2 = (u32)f2bf(o[4]) | ((u32)f2bf(o[5]) << 16);
  u32 w3 = (u32)f2bf(o[6]) | ((u32)f2bf(o[7]) << 16);
  *(uint4*)(out + (size_t)row * Cc + lane * 8) = make_uint4(w0, w1, w2, w3);
}

// ---------- GEMM: out[M,N] = A[M,K](bf16) @ Bt[N,K](bf16)^T + bias ----------
// 256x256 tile, BK=64, 8 waves (4M x 2N), 512 threads, 128 KiB LDS.
// Zigzag 4-phase schedule per K-tile: each fragment read from LDS ONCE
// (28 ds_read_b128/K-tile/wave vs 48 in the naive quadrant split) and
// reused from registers across adjacent phases:
//   ph0 (Q00): read A01 + B_lo -> MFMA m01 x n0-3
//   ph1 (Q10): read A23, reuse B_lo -> MFMA m23 x n0-3
//   ph2 (Q11): read B_hi, reuse A23 -> MFMA m23 x n4-7
//   ph3 (Q01): re-read A01, reuse B_hi -> MFMA m01 x n4-7
// Peak operand liveness ~48 VGPR (A re-read instead of keeping both B
// halves live, to stay under the 256-VGPR 2-waves/SIMD cliff).
// Staging choreography UNCHANGED from verified version (tile t, p=t&1):
//   ph0: A q0,q1(t+1)->buf 1-p   ph1: A q2,q3(t+1)->buf 1-p
//   ph2: B q1,q3(t+1)->buf 1-p   ph3: B q0,q2(t+2)->buf p (freed after ph0)
// counted vmcnt(4) at ph0 and ph3; tail tiles vmcnt(2)/vmcnt(0).
// MODE 0: -> bf16   MODE 1: gelu -> bf16   MODE 2: +res(fp32) -> bf16
// MODE 3: +res(bf16) -> fp32 (direct full-line stores)
template<int MODE>
__global__ __launch_bounds__(512, 2)
void gemm_bt(const u16* __restrict__ A, const u16* __restrict__ Bt,
             const float* __restrict__ bias, const void* __restrict__ res,
             void* __restrict__ outp, int M, int N, int K, int nbn) {
  (void)M;
  __shared__ __align__(16) u16 smem[65536];   // 128 KiB: 2 x (A 32K + B 32K)

  // ---- bijective XCD swizzle (m204), nt fastest for A-panel L2 reuse ----
  const int nwg = gridDim.x;
  const int bq = nwg >> 3, brr = nwg & 7;
  const int xcd = blockIdx.x & 7, bi = blockIdx.x >> 3;
  const int wg = (xcd < brr ? xcd * (bq + 1) : brr * (bq + 1) + (xcd - brr) * bq) + bi;
  const int mt = wg / nbn;
  const int nt = wg - mt * nbn;
  const int m0 = mt << 8;
  const int n0 = nt << 8;

  const int tid  = threadIdx.x;
  const int lane = tid & 63;
  const int wave = tid >> 6;
  const int wm4  = wave >> 1;          // 0..3  M quarter (64 rows)
  const int wn2  = wave & 1;           // 0..1  N half (128 cols)
  const int quad = lane >> 4;
  const int l16  = lane & 15;
  const int nT   = K >> 6;             // K-tiles of 64

  // staging source coords: inverse of the st_16x32 swizzle (u16 units).
  int lu = tid << 3;
  lu ^= ((lu >> 8) & 1) << 4;
  const int sr = ((lu >> 10) << 4) | ((lu >> 5) & 15);   // row 0..63
  const int sc = (((lu >> 9) & 1) << 5) | (lu & 31);     // col 0..63 (x8 aligned)

  // swizzled ds_read lane offset within a (quarter, rb, ks) 1KB block
  const int lrow = ((l16 << 5) | (quad << 3)) ^ ((l16 & 8) << 1);

  const u16* Ag = A  + (size_t)(m0 + sr) * K + sc;
  const u16* Bg = Bt + (size_t)(n0 + sr) * K + sc;

#define STAGE_A(kt, q, buf) gld_lds16(Ag + (size_t)((q) << 6) * K + ((kt) << 6), \
                                      &smem[((buf) << 15) + ((q) << 12) + (wave << 9)])
#define STAGE_B(kt, q, buf) gld_lds16(Bg + (size_t)((q) << 6) * K + ((kt) << 6), \
                                      &smem[((buf) << 15) + 16384 + ((q) << 12) + (wave << 9)])
#define RD_A(m, ks)  (*(const short8*)&smem[abase + ((m) << 10) + ((ks) << 9) + lrow])
#define RD_B(h, n, ks) (*(const short8*)&smem[bbase + ((h) << 12) + ((n) << 10) + ((ks) << 9) + lrow])
#define MFMA_PH(AF, ACM, BF, ACN)                                          \
  __builtin_amdgcn_s_barrier();                                            \
  asm volatile("s_waitcnt lgkmcnt(0)" ::: "memory");                       \
  __builtin_amdgcn_sched_barrier(0);                                       \
  __builtin_amdgcn_s_setprio(1);                                           \
  _Pragma("unroll")                                                        \
  for (int n = 0; n < 4; ++n)                                              \
    _Pragma("unroll")                                                      \
    for (int m = 0; m < 2; ++m)                                            \
      _Pragma("unroll")                                                    \
      for (int ks = 0; ks < 2; ++ks)                                       \
        acc[(ACM) + m][(ACN) + n] =                                        \
            __builtin_amdgcn_mfma_f32_16x16x32_bf16(                       \
                AF[m][ks], BF[n][ks], acc[(ACM) + m][(ACN) + n], 0, 0, 0); \
  __builtin_amdgcn_s_setprio(0);                                           \
  __builtin_amdgcn_s_barrier();

  floatx4 acc[4][8];
  #pragma unroll
  for (int i = 0; i < 4; i++)
    #pragma unroll
    for (int j = 0; j < 8; j++) acc[i][j] = (floatx4)0.f;

  // ---- prologue: tile0 (A q0-3, B even, B odd), then tile1 B even ----
  STAGE_A(0, 0, 0); STAGE_A(0, 1, 0); STAGE_A(0, 2, 0); STAGE_A(0, 3, 0);
  STAGE_B(0, 0, 0); STAGE_B(0, 2, 0);
  STAGE_B(0, 1, 0); STAGE_B(0, 3, 0);
  if (nT > 1) { STAGE_B(1, 0, 1); STAGE_B(1, 2, 1); }
  asm volatile("s_waitcnt vmcnt(4)" ::: "memory");   // A(0)+Beven(0) landed
  __builtin_amdgcn_s_barrier();

  for (int t = 0; t < nT; ++t) {
    const int cbuf  = t & 1;
    const int abase = (cbuf << 15) + (wm4 << 12);
    const int bbase = (cbuf << 15) + 16384 + (wn2 << 13);
    const bool s1 = (t + 1) < nT;
    const bool s2 = (t + 2) < nT;
    short8 a01[2][2], a23[2][2], bl[4][2], bh[4][2];

    // ---- ph0 (Q00): read A01 + B_lo; stage A(t+1) q0,q1 ----
    #pragma unroll
    for (int m = 0; m < 2; ++m)
      #pragma unroll
      for (int ks = 0; ks < 2; ++ks) a01[m][ks] = RD_A(m, ks);
    #pragma unroll
    for (int n = 0; n < 4; ++n)
      #pragma unroll
      for (int ks = 0; ks < 2; ++ks) bl[n][ks] = RD_B(0, n, ks);
    if (s1) {
      STAGE_A(t + 1, 0, cbuf ^ 1); STAGE_A(t + 1, 1, cbuf ^ 1);
      asm volatile("s_waitcnt vmcnt(4)" ::: "memory");   // Bodd(t) landed
    } else {
      asm volatile("s_waitcnt vmcnt(0)" ::: "memory");   // last tile: drain
    }
    MFMA_PH(a01, 0, bl, 0)

    // ---- ph1 (Q10): read A23, reuse B_lo; stage A(t+1) q2,q3 ----
    #pragma unroll
    for (int m = 0; m < 2; ++m)
      #pragma unroll
      for (int ks = 0; ks < 2; ++ks) a23[m][ks] = RD_A(2 + m, ks);
    if (s1) { STAGE_A(t + 1, 2, cbuf ^ 1); STAGE_A(t + 1, 3, cbuf ^ 1); }
    MFMA_PH(a23, 2, bl, 0)

    // ---- ph2 (Q11): read B_hi, reuse A23; stage B(t+1) odd ----
    #pragma unroll
    for (int n = 0; n < 4; ++n)
      #pragma unroll
      for (int ks = 0; ks < 2; ++ks) bh[n][ks] = RD_B(1, n, ks);
    if (s1) { STAGE_B(t + 1, 1, cbuf ^ 1); STAGE_B(t + 1, 3, cbuf ^ 1); }
    MFMA_PH(a23, 2, bh, 4)

    // ---- ph3 (Q01): re-read A01, reuse B_hi; stage B(t+2) even -> cbuf ----
    #pragma unroll
    for (int m = 0; m < 2; ++m)
      #pragma unroll
      for (int ks = 0; ks < 2; ++ks) a01[m][ks] = RD_A(m, ks);
    if (s2) {
      STAGE_B(t + 2, 0, cbuf); STAGE_B(t + 2, 2, cbuf);  // over Beven(t), freed ph0
      asm volatile("s_waitcnt vmcnt(4)" ::: "memory");   // A(t+1)+Beven(t+1) landed
    } else if (s1) {
      asm volatile("s_waitcnt vmcnt(2)" ::: "memory");   // tail: fewer in flight
    }
    MFMA_PH(a01, 0, bh, 4)
  }
#undef STAGE_A
#undef STAGE_B
#undef RD_A
#undef RD_B
#undef MFMA_PH

  if (MODE == 3) {
    // fp32 direct stores: 16 lanes x 4B consecutive = full 64B lines.
    const int mrow = m0 + (wm4 << 6) + (quad << 2);
    const int ncol = n0 + (wn2 << 7) + l16;
    #pragma unroll
    for (int ni = 0; ni < 8; ++ni) {
      const int n = ncol + ni * 16;
      const float bv = bias[n];
      #pragma unroll
      for (int mi = 0; mi < 4; ++mi)
        #pragma unroll
        for (int r = 0; r < 4; ++r) {
          const size_t idx = (size_t)(mrow + mi * 16 + r) * N + n;
          ((float*)outp)[idx] = acc[mi][ni][r] + bv + bf2f(((const u16*)res)[idx]);
        }
    }
  } else {
    // stage bf16 C in two 128-row halves through LDS, 16B/lane writeout
    #pragma unroll
    for (int h = 0; h < 2; ++h) {
      __syncthreads();
      if ((wm4 >> 1) == h) {
        const int rb0 = ((wm4 & 1) << 6) + (quad << 2);
        #pragma unroll
        for (int ni = 0; ni < 8; ++ni) {
          const int col = (wn2 << 7) + ni * 16 + l16;
          const float bv = bias[n0 + col];
          #pragma unroll
          for (int mi = 0; mi < 4; ++mi)
            #pragma unroll
            for (int r = 0; r < 4; ++r) {
              float v = acc[mi][ni][r] + bv;
              if (MODE == 1) v = gelu_f(v);
              smem[(rb0 + mi * 16 + r) * CSTR2 + col] = f2bf(v);
            }
        }
      }
      __syncthreads();
      const int trow = tid >> 5;            // 0..15
      const int tcol = (tid & 31) << 3;     // u16 col
      #pragma unroll
      for (int it = 0; it < 8; ++it) {
        const int row = it * 16 + trow;
        uint4 w = *(const uint4*)&smem[row * CSTR2 + tcol];
        const size_t gi = (size_t)(m0 + (h << 7) + row) * N + n0 + tcol;
        if (MODE == 2) {
          const float* rp = (const float*)res + gi;
          float4 ra  = *(const float4*)rp;
          float4 rb2 = *(const float4*)(rp + 4);
          u32 w0 = (u32)f2bf(bf2f_lo(w.x) + ra.x)  | ((u32)f2bf(bf2f_hi(w.x) + ra.y)  << 16);
          u32 w1 = (u32)f2bf(bf2f_lo(w.y) + ra.z)  | ((u32)f2bf(bf2f_hi(w.y) + ra.w)  << 16);
          u32 w2 = (u32)f2bf(bf2f_lo(w.z) + rb2.x) | ((u32)f2bf(bf2f_hi(w.z) + rb2.y) << 16);
          u32 w3 = (u32)f2bf(bf2f_lo(w.w) + rb2.z) | ((u32)f2bf(bf2f_hi(w.w) + rb2.w) << 16);
          *(uint4*)((u16*)outp + gi) = make_uint4(w0, w1, w2, w3);
        } else {
          *(uint4*)((u16*)outp + gi) = w;
        }
      }
    }
  }
}

// ---------- windowed attention, one wave per (window, head) ----------
__global__ __launch_bounds__(64)
void attn_k(const u16* __restrict__ QKV, const float* __restrict__ rel,
            u16* __restrict__ O) {
  const int win  = blockIdx.x;          // 0..1023
  const int head = blockIdx.y;          // 0..15
  const int b    = win >> 6;
  const int wh   = (win >> 3) & 7;
  const int ww   = win & 7;
  const int lane = threadIdx.x;

  __shared__ float Ks[49][36];
  __shared__ float Vs[49][36];

  const bool active = lane < 49;
  size_t rowq = 0, rowo = 0;
  float q[32];
  if (active) {
    const int i = lane / 7, j = lane - 7 * (lane / 7);
    const int l = (wh * 7 + i) * Ww + ww * 7 + j;
    const size_t gr = (size_t)(b * Ll + l);
    rowq = gr * 1536 + head * HDd;
    rowo = gr * 512  + head * HDd;
    const uint4* qp = (const uint4*)(QKV + rowq);
    const uint4* kp = (const uint4*)(QKV + rowq + 512);
    const uint4* vp = (const uint4*)(QKV + rowq + 1024);
    #pragma unroll
    for (int c = 0; c < 4; c++) {
      uint4 qv = qp[c], kv = kp[c], vv = vp[c];
      q[c*8+0] = bf2f_lo(qv.x) * SCALE; q[c*8+1] = bf2f_hi(qv.x) * SCALE;
      q[c*8+2] = bf2f_lo(qv.y) * SCALE; q[c*8+3] = bf2f_hi(qv.y) * SCALE;
      q[c*8+4] = bf2f_lo(qv.z) * SCALE; q[c*8+5] = bf2f_hi(qv.z) * SCALE;
      q[c*8+6] = bf2f_lo(qv.w) * SCALE; q[c*8+7] = bf2f_hi(qv.w) * SCALE;
      *(float4*)&Ks[lane][c*8]   = make_float4(bf2f_lo(kv.x), bf2f_hi(kv.x),
                                               bf2f_lo(kv.y), bf2f_hi(kv.y));
      *(float4*)&Ks[lane][c*8+4] = make_float4(bf2f_lo(kv.z), bf2f_hi(kv.z),
                                               bf2f_lo(kv.w), bf2f_hi(kv.w));
      *(float4*)&Vs[lane][c*8]   = make_float4(bf2f_lo(vv.x), bf2f_hi(vv.x),
                                               bf2f_lo(vv.y), bf2f_hi(vv.y));
      *(float4*)&Vs[lane][c*8+4] = make_float4(bf2f_lo(vv.z), bf2f_hi(vv.z),
                                               bf2f_lo(vv.w), bf2f_hi(vv.w));
    }
  }
  __syncthreads();
  if (!active) return;

  const float* rb = rel + ((size_t)head * 49 + lane) * 49;
  float s[49];
  float mx = -1e30f;
  #pragma unroll
  for (int m = 0; m < 49; m++) {
    float d = 0.f;
    #pragma unroll
    for (int c = 0; c < 8; c++) {
      float4 kk = *(const float4*)&Ks[m][c*4];
      d += q[c*4+0]*kk.x + q[c*4+1]*kk.y + q[c*4+2]*kk.z + q[c*4+3]*kk.w;
    }
    d += rb[m];
    s[m] = d;
    mx = fmaxf(mx, d);
  }
  float sum = 0.f;
  #pragma unroll
  for (int m = 0; m < 49; m++) { float e = __expf(s[m] - mx); s[m] = e; sum += e; }
  const float inv = 1.f / sum;

  float acc[32];
  #pragma unroll
  for (int d = 0; d < 32; d++) acc[d] = 0.f;
  #pragma unroll
  for (int m = 0; m < 49; m++) {
    const float p = s[m];
    #pragma unroll
    for (int c = 0; c < 8; c++) {
      float4 vv = *(const float4*)&Vs[m][c*4];
      acc[c*4+0] += p*vv.x; acc[c*4+1] += p*vv.y;
      acc[c*4+2] += p*vv.z; acc[c*4+3] += p*vv.w;
    }
  }
  uint4* op = (uint4*)(O + rowo);
  #pragma unroll
  for (int c = 0; c < 4; c++) {
    u32 w0 = (u32)f2bf(acc[c*8+0]*inv) | ((u32)f2bf(acc[c*8+1]*inv) << 16);
    u32 w1 = (u32)f2bf(acc[c*8+2]*inv) | ((u32)f2bf(acc[c*8+3]*inv) << 16);
    u32 w2 = (u32)f2bf(acc[c*8+4]*inv) | ((u32)f2bf(acc[c*8+5]*inv) << 16);
    u32 w3 = (u32)f2bf(acc[c*8+6]*inv) | ((u32)f2bf(acc[c*8+7]*inv) << 16);
    op[c] = make_uint4(w0, w1, w2, w3);
  }
}

// ---------- launch ----------
extern "C" void kernel_launch(void* const* d_in, const int* in_sizes, int n_in,
                              void* d_out, int out_size, void* d_ws, size_t ws_size,
                              hipStream_t stream) {
  (void)in_sizes; (void)n_in; (void)out_size; (void)ws_size;
  const float* x    = (const float*)d_in[0];
  const float* Wq   = (const float*)d_in[1];
  const float* bq   = (const float*)d_in[2];
  const float* Wk   = (const float*)d_in[3];
  const float* bk   = (const float*)d_in[4];
  const float* Wv   = (const float*)d_in[5];
  const float* bv   = (const float*)d_in[6];
  const float* Wp   = (const float*)d_in[7];
  const float* bp   = (const float*)d_in[8];
  const float* rel  = (const float*)d_in[9];
  const float* g1   = (const float*)d_in[10];
  const float* b1   = (const float*)d_in[11];
  const float* g2   = (const float*)d_in[12];
  const float* b2   = (const float*)d_in[13];
  const float* W1   = (const float*)d_in[14];
  const float* bfc1 = (const float*)d_in[15];
  const float* W2   = (const float*)d_in[16];
  const float* bfc2 = (const float*)d_in[17];
  float* out = (float*)d_out;

  // workspace layout (u16 units)
  u16* wQKV = (u16*)d_ws;                          // 1536*512
  u16* wWp  = wQKV + (size_t)1536*512;             // 512*512
  u16* wW1  = wWp  + (size_t)512*512;              // 2048*512
  u16* wW2  = wW1  + (size_t)2048*512;             // 512*2048
  float* bqkv = (float*)(wW2 + (size_t)512*2048);  // 1536 fp32
  u16* hbuf = (u16*)(bqkv + 1536);                 // M*512 (LN1 out; later LN2 out)
  u16* QKVb = hbuf + (size_t)Mm * Cc;              // M*1536 (later: MLP hidden part)
  u16* Obuf = QKVb + (size_t)Mm * 1536;            // M*512
  u16* x2bf = Obuf + (size_t)Mm * Cc;              // M*512 bf16 residual
  u16* hid  = QKVb;                                // M*2048 overlays QKVb+Obuf
  u16* h2   = hbuf;

  // weights -> bf16 transposed (QKV fused into 1536 rows)
  wcvt_k<<<(512*512)/256,  256, 0, stream>>>(Wq, wQKV,              512, 512);
  wcvt_k<<<(512*512)/256,  256, 0, stream>>>(Wk, wQKV + 512*512,    512, 512);
  wcvt_k<<<(512*512)/256,  256, 0, stream>>>(Wv, wQKV + 2*512*512,  512, 512);
  wcvt_k<<<(512*512)/256,  256, 0, stream>>>(Wp, wWp, 512, 512);
  wcvt_k<<<(512*2048)/256, 256, 0, stream>>>(W1, wW1, 512, 2048);
  wcvt_k<<<(512*2048)/256, 256, 0, stream>>>(W2, wW2, 2048, 512);
  bcat_k<<<6, 256, 0, stream>>>(bq, bk, bv, bqkv);

  // LN1
  ln_k<<<Mm/4, 256, 0, stream>>>(x, g1, b1, hbuf);

  // fused QKV projection: (M,1536) = 196 x 6 tiles of 256
  gemm_bt<0><<<196*6, 512, 0, stream>>>(hbuf, wQKV, bqkv, nullptr, QKVb,
                                        Mm, 1536, 512, 6);

  // attention
  attn_k<<<dim3(1024, 16), 64, 0, stream>>>(QKVb, rel, Obuf);

  // proj + residual(x fp32) -> x2 bf16
  gemm_bt<2><<<196*2, 512, 0, stream>>>(Obuf, wWp, bp, x, x2bf,
                                        Mm, 512, 512, 2);

  // LN2 (bf16 in)
  ln_bf_k<<<Mm/4, 256, 0, stream>>>(x2bf, g2, b2, h2);

  // MLP
  gemm_bt<1><<<196*8, 512, 0, stream>>>(h2, wW1, bfc1, nullptr, hid,
                                        Mm, 2048, 512, 8);
  gemm_bt<3><<<196*2, 512, 0, stream>>>(hid, wW2, bfc2, x2bf, out,
                                        Mm, 512, 2048, 2);
}

// Round 3
// 910.566 us; speedup vs baseline: 1.2374x; 1.1951x over previous
//
#include <hip/hip_runtime.h>

typedef unsigned short u16;
typedef unsigned int   u32;

using short8  = __attribute__((ext_vector_type(8))) short;
using floatx4 = __attribute__((ext_vector_type(4))) float;

// ---------- constants ----------
#define Bb   16
#define Hh   56
#define Ww   56
#define Cc   512
#define NHh  16
#define HDd  32
#define HIDh 2048
#define Ll   (Hh*Ww)          // 3136
#define Mm   (Bb*Ll)          // 50176
#define SCALE 0.17677669529663687f
#define CSTR 136              // C-tile LDS row stride (u16): 16B-aligned, bank-rotating

// ---------- helpers ----------
__device__ __forceinline__ u16 f2bf(float f) {
  union { float f; u32 u; } v; v.f = f;
  u32 r = (v.u + 0x7fffu + ((v.u >> 16) & 1u)) >> 16;
  return (u16)r;
}
__device__ __forceinline__ float bf2f(u16 u) {
  union { u32 u; float f; } v; v.u = ((u32)u) << 16; return v.f;
}
__device__ __forceinline__ float bf2f_lo(u32 u) {
  union { u32 u; float f; } v; v.u = u << 16; return v.f;
}
__device__ __forceinline__ float bf2f_hi(u32 u) {
  union { u32 u; float f; } v; v.u = u & 0xffff0000u; return v.f;
}
// gelu with A&S 7.1.26 erf (|err| < 1.5e-7): ~2x cheaper than libm erff.
__device__ __forceinline__ float gelu_f(float x) {
  const float z  = x * 0.70710678118654752f;
  const float az = fabsf(z);
  const float t  = __builtin_amdgcn_rcpf(fmaf(0.3275911f, az, 1.f));
  float p = fmaf(1.061405429f, t, -1.453152027f);
  p = fmaf(p, t, 1.421413741f);
  p = fmaf(p, t, -0.284496736f);
  p = fmaf(p, t, 0.254829592f);
  const float e = p * t * __expf(-z * z);     // 1 - erf(|z|)
  float erfz = 1.f - e;
  erfz = copysignf(erfz, z);
  return 0.5f * x * (1.f + erfz);
}
__device__ __forceinline__ void gld_lds16(const u16* g, u16* l) {
  __builtin_amdgcn_global_load_lds(
      (__attribute__((address_space(1))) void*)(void*)g,
      (__attribute__((address_space(3))) void*)(void*)l,
      16, 0, 0);
}

// ---------- weight convert+transpose: Wt[n][k] = bf16(W[k][n]) ----------
__global__ void wcvt_k(const float* __restrict__ W, u16* __restrict__ Wt,
                       int K, int N) {
  int idx = blockIdx.x * 256 + threadIdx.x;     // over N*K
  int n = idx / K;
  int k = idx - n * K;
  Wt[idx] = f2bf(W[(size_t)k * N + n]);
}

// ---------- concat 3 bias vectors (512 each) ----------
__global__ void bcat_k(const float* __restrict__ a, const float* __restrict__ b,
                       const float* __restrict__ c, float* __restrict__ o) {
  int i = blockIdx.x * 256 + threadIdx.x;   // 0..1535
  float v = (i < 512) ? a[i] : (i < 1024) ? b[i - 512] : c[i - 1024];
  o[i] = v;
}

// ---------- layernorm fp32 in -> bf16 out, one wave per row ----------
__global__ __launch_bounds__(256)
void ln_k(const float* __restrict__ x, const float* __restrict__ g,
          const float* __restrict__ b, u16* __restrict__ out) {
  const int row  = blockIdx.x * 4 + (threadIdx.x >> 6);
  const int lane = threadIdx.x & 63;
  const float* xr = x + (size_t)row * Cc + lane * 8;
  float4 v0 = *(const float4*)xr;
  float4 v1 = *(const float4*)(xr + 4);
  float s  = v0.x+v0.y+v0.z+v0.w + v1.x+v1.y+v1.z+v1.w;
  float s2 = v0.x*v0.x+v0.y*v0.y+v0.z*v0.z+v0.w*v0.w
           + v1.x*v1.x+v1.y*v1.y+v1.z*v1.z+v1.w*v1.w;
  #pragma unroll
  for (int off = 32; off >= 1; off >>= 1) {
    s  += __shfl_xor(s,  off);
    s2 += __shfl_xor(s2, off);
  }
  float mu  = s  * (1.f/512.f);
  float var = s2 * (1.f/512.f) - mu*mu;
  float rs  = rsqrtf(var + 1e-5f);
  float4 ga = *(const float4*)(g + lane*8);
  float4 gb = *(const float4*)(g + lane*8 + 4);
  float4 ba = *(const float4*)(b + lane*8);
  float4 bb = *(const float4*)(b + lane*8 + 4);
  float o0 = (v0.x-mu)*rs*ga.x + ba.x;
  float o1 = (v0.y-mu)*rs*ga.y + ba.y;
  float o2 = (v0.z-mu)*rs*ga.z + ba.z;
  float o3 = (v0.w-mu)*rs*ga.w + ba.w;
  float o4 = (v1.x-mu)*rs*gb.x + bb.x;
  float o5 = (v1.y-mu)*rs*gb.y + bb.y;
  float o6 = (v1.z-mu)*rs*gb.z + bb.z;
  float o7 = (v1.w-mu)*rs*gb.w + bb.w;
  u32 w0 = (u32)f2bf(o0) | ((u32)f2bf(o1) << 16);
  u32 w1 = (u32)f2bf(o2) | ((u32)f2bf(o3) << 16);
  u32 w2 = (u32)f2bf(o4) | ((u32)f2bf(o5) << 16);
  u32 w3 = (u32)f2bf(o6) | ((u32)f2bf(o7) << 16);
  *(uint4*)(out + (size_t)row * Cc + lane * 8) = make_uint4(w0, w1, w2, w3);
}

// ---------- layernorm bf16 in -> bf16 out ----------
__global__ __launch_bounds__(256)
void ln_bf_k(const u16* __restrict__ x, const float* __restrict__ g,
             const float* __restrict__ b, u16* __restrict__ out) {
  const int row  = blockIdx.x * 4 + (threadIdx.x >> 6);
  const int lane = threadIdx.x & 63;
  uint4 xv = *(const uint4*)(x + (size_t)row * Cc + lane * 8);
  float v[8];
  v[0]=bf2f_lo(xv.x); v[1]=bf2f_hi(xv.x); v[2]=bf2f_lo(xv.y); v[3]=bf2f_hi(xv.y);
  v[4]=bf2f_lo(xv.z); v[5]=bf2f_hi(xv.z); v[6]=bf2f_lo(xv.w); v[7]=bf2f_hi(xv.w);
  float s = 0.f, s2 = 0.f;
  #pragma unroll
  for (int i = 0; i < 8; i++) { s += v[i]; s2 += v[i]*v[i]; }
  #pragma unroll
  for (int off = 32; off >= 1; off >>= 1) {
    s  += __shfl_xor(s,  off);
    s2 += __shfl_xor(s2, off);
  }
  float mu  = s  * (1.f/512.f);
  float var = s2 * (1.f/512.f) - mu*mu;
  float rs  = rsqrtf(var + 1e-5f);
  float4 ga = *(const float4*)(g + lane*8);
  float4 gb = *(const float4*)(g + lane*8 + 4);
  float4 ba = *(const float4*)(b + lane*8);
  float4 bb = *(const float4*)(b + lane*8 + 4);
  float o[8];
  o[0]=(v[0]-mu)*rs*ga.x+ba.x; o[1]=(v[1]-mu)*rs*ga.y+ba.y;
  o[2]=(v[2]-mu)*rs*ga.z+ba.z; o[3]=(v[3]-mu)*rs*ga.w+ba.w;
  o[4]=(v[4]-mu)*rs*gb.x+bb.x; o[5]=(v[5]-mu)*rs*gb.y+bb.y;
  o[6]=(v[6]-mu)*rs*gb.z+bb.z; o[7]=(v[7]-mu)*rs*gb.w+bb.w;
  u32 w0 = (u32)f2bf(o[0]) | ((u32)f2bf(o[1]) << 16);
  u32 w1 = (u32)f2bf(o[2]) | ((u32)f2bf(o[3]) << 16);
  u32 w2 = (u32)f2bf(o[4]) | ((u32)f2bf(o[5]) << 16);
  u32 w3 = (u32)f2bf(o[6]) | ((u32)f2bf(o[7]) << 16);
  *(uint4*)(out + (size_t)row * Cc + lane * 8) = make_uint4(w0, w1, w2, w3);
}

// ---------- GEMM: out[M,N] = A[M,K](bf16) @ Bt[N,K](bf16)^T + bias ----------
// 128x128 tile, BK=32, 256 threads (4 waves, 2x2), XCD-aware swizzle.
// Double-buffered LDS (2 x 16 KB, aliased under the 34.8 KB C-stage region)
// with counted-wait single-barrier K-loop (T3-minimum): stage tile t+1 at
// the TOP of step t into the alternate buffer; the end-of-step vmcnt(0)
// drains loads that already had the whole ds_read+MFMA phase to land.
// One s_barrier per K-step (vs 2 full-drain __syncthreads before).
// __launch_bounds__(256,4): LDS 34816 B -> 4 blocks/CU for TLP overlap of
// prologue/epilogue across blocks.
// MODE 0: -> bf16   MODE 1: gelu -> bf16   MODE 2: +res(fp32) -> bf16
// MODE 3: +res(bf16) -> fp32 (direct stores: fp32 rows are full-line already)
template<int MODE>
__global__ __launch_bounds__(256, 4)
void gemm_bt(const u16* __restrict__ A, const u16* __restrict__ Bt,
             const float* __restrict__ bias, const void* __restrict__ res,
             void* __restrict__ outp, int M, int N, int K, int nbn) {
  (void)M;
  __shared__ __align__(16) u16 smem[128 * CSTR];   // 34816 B; aliases dbuf + C

  const int b   = blockIdx.x;
  const int xcd = b & 7;
  const int s   = b >> 3;
  const int mt  = (s / nbn) * 8 + xcd;
  const int nt  = s - (s / nbn) * nbn;
  const int m0  = mt * 128;
  const int n0  = nt * 128;

  const int tid  = threadIdx.x;
  const int lane = tid & 63;
  const int wave = tid >> 6;
  const int wm = (wave >> 1) * 64;
  const int wn = (wave & 1) * 64;
  const int quad = lane >> 4;
  const int l16  = lane & 15;

  floatx4 acc[4][4];
  #pragma unroll
  for (int i = 0; i < 4; i++)
    #pragma unroll
    for (int j = 0; j < 4; j++) acc[i][j] = (floatx4)0.f;

  const int r0  = tid >> 2;
  const int cc0 = (((tid & 3) ^ ((r0 >> 1) & 3)) * 8);   // XOR-swizzled k-offset
  const u16* Ag = A  + (size_t)m0 * K;
  const u16* Bg = Bt + (size_t)n0 * K;

  const int fswz = (l16 >> 1) & 3;
  const int aoff = (quad ^ fswz) * 8;

  // dbuf layout (u16): buf0 = [A 4096 | B 4096] at 0, buf1 at 8192.
#define STG(kk, bufo) do {                                                        \
    gld_lds16(Ag + (size_t)r0        * K + (kk) + cc0, &smem[(bufo) + wave * 512]);        \
    gld_lds16(Ag + (size_t)(r0 + 64) * K + (kk) + cc0, &smem[(bufo) + 2048 + wave * 512]); \
    gld_lds16(Bg + (size_t)r0        * K + (kk) + cc0, &smem[(bufo) + 4096 + wave * 512]); \
    gld_lds16(Bg + (size_t)(r0 + 64) * K + (kk) + cc0, &smem[(bufo) + 6144 + wave * 512]); \
  } while (0)

  STG(0, 0);
  asm volatile("s_waitcnt vmcnt(0)" ::: "memory");
  __builtin_amdgcn_s_barrier();

  for (int k0 = 0; k0 < K; k0 += 32) {
    const int bufo = ((k0 >> 5) & 1) * 8192;
    if (k0 + 32 < K) STG(k0 + 32, bufo ^ 8192);
    const u16* As = &smem[bufo];
    const u16* Bs = &smem[bufo + 4096];
    short8 af[4], bf[4];
    #pragma unroll
    for (int mi = 0; mi < 4; mi++)
      af[mi] = *(const short8*)&As[(wm + mi*16 + l16) * 32 + aoff];
    #pragma unroll
    for (int ni = 0; ni < 4; ni++)
      bf[ni] = *(const short8*)&Bs[(wn + ni*16 + l16) * 32 + aoff];
    #pragma unroll
    for (int mi = 0; mi < 4; mi++)
      #pragma unroll
      for (int ni = 0; ni < 4; ni++)
        acc[mi][ni] = __builtin_amdgcn_mfma_f32_16x16x32_bf16(
            af[mi], bf[ni], acc[mi][ni], 0, 0, 0);
    asm volatile("s_waitcnt vmcnt(0)" ::: "memory");   // t+1 loads landed
    __builtin_amdgcn_s_barrier();
  }
#undef STG

  if (MODE == 3) {
    // fp32 direct stores: 16 lanes x 4B consecutive = full 64B lines.
    const int mrow = m0 + wm + quad * 4;
    const int ncol = n0 + wn + l16;
    #pragma unroll
    for (int ni = 0; ni < 4; ni++) {
      const int n = ncol + ni * 16;
      const float bv = bias[n];
      #pragma unroll
      for (int mi = 0; mi < 4; mi++)
        #pragma unroll
        for (int r = 0; r < 4; r++) {
          const size_t idx = (size_t)(mrow + mi * 16 + r) * N + n;
          ((float*)outp)[idx] = acc[mi][ni][r] + bv + bf2f(((const u16*)res)[idx]);
        }
    }
  } else {
    // stage bf16 C-tile in LDS, then coalesced 16B/lane writeout
    #pragma unroll
    for (int ni = 0; ni < 4; ni++) {
      const int col = wn + ni * 16 + l16;
      const float bv = bias[n0 + col];
      #pragma unroll
      for (int mi = 0; mi < 4; mi++)
        #pragma unroll
        for (int r = 0; r < 4; r++) {
          float v = acc[mi][ni][r] + bv;
          if (MODE == 1) v = gelu_f(v);
          smem[(wm + mi * 16 + quad * 4 + r) * CSTR + col] = f2bf(v);
        }
    }
    __syncthreads();
    const int trow = tid >> 4;            // 0..15
    const int tcol = (tid & 15) * 8;      // u16 col
    #pragma unroll
    for (int it = 0; it < 8; it++) {
      const int row = it * 16 + trow;
      uint4 w = *(const uint4*)&smem[row * CSTR + tcol];
      const size_t gi = (size_t)(m0 + row) * N + n0 + tcol;
      if (MODE == 2) {
        const float* rp = (const float*)res + gi;
        float4 ra = *(const float4*)rp;
        float4 rb = *(const float4*)(rp + 4);
        u32 w0 = (u32)f2bf(bf2f_lo(w.x) + ra.x) | ((u32)f2bf(bf2f_hi(w.x) + ra.y) << 16);
        u32 w1 = (u32)f2bf(bf2f_lo(w.y) + ra.z) | ((u32)f2bf(bf2f_hi(w.y) + ra.w) << 16);
        u32 w2 = (u32)f2bf(bf2f_lo(w.z) + rb.x) | ((u32)f2bf(bf2f_hi(w.z) + rb.y) << 16);
        u32 w3 = (u32)f2bf(bf2f_lo(w.w) + rb.z) | ((u32)f2bf(bf2f_hi(w.w) + rb.w) << 16);
        *(uint4*)((u16*)outp + gi) = make_uint4(w0, w1, w2, w3);
      } else {
        *(uint4*)((u16*)outp + gi) = w;
      }
    }
  }
}

// ---------- windowed attention, one wave per (window, head) ----------
// QKV interleaved bf16 (M, 1536): [Q 512 | K 512 | V 512]; out (M,512) bf16.
__global__ __launch_bounds__(64)
void attn_k(const u16* __restrict__ QKV, const float* __restrict__ rel,
            u16* __restrict__ O) {
  const int win  = blockIdx.x;          // 0..1023
  const int head = blockIdx.y;          // 0..15
  const int b    = win >> 6;
  const int wh   = (win >> 3) & 7;
  const int ww   = win & 7;
  const int lane = threadIdx.x;

  __shared__ float Ks[49][36];
  __shared__ float Vs[49][36];

  const bool active = lane < 49;
  size_t rowq = 0, rowo = 0;
  float q[32];
  if (active) {
    const int i = lane / 7, j = lane - 7 * (lane / 7);
    const int l = (wh * 7 + i) * Ww + ww * 7 + j;
    const size_t gr = (size_t)(b * Ll + l);
    rowq = gr * 1536 + head * HDd;
    rowo = gr * 512  + head * HDd;
    const uint4* qp = (const uint4*)(QKV + rowq);
    const uint4* kp = (const uint4*)(QKV + rowq + 512);
    const uint4* vp = (const uint4*)(QKV + rowq + 1024);
    #pragma unroll
    for (int c = 0; c < 4; c++) {
      uint4 qv = qp[c], kv = kp[c], vv = vp[c];
      q[c*8+0] = bf2f_lo(qv.x) * SCALE; q[c*8+1] = bf2f_hi(qv.x) * SCALE;
      q[c*8+2] = bf2f_lo(qv.y) * SCALE; q[c*8+3] = bf2f_hi(qv.y) * SCALE;
      q[c*8+4] = bf2f_lo(qv.z) * SCALE; q[c*8+5] = bf2f_hi(qv.z) * SCALE;
      q[c*8+6] = bf2f_lo(qv.w) * SCALE; q[c*8+7] = bf2f_hi(qv.w) * SCALE;
      *(float4*)&Ks[lane][c*8]   = make_float4(bf2f_lo(kv.x), bf2f_hi(kv.x),
                                               bf2f_lo(kv.y), bf2f_hi(kv.y));
      *(float4*)&Ks[lane][c*8+4] = make_float4(bf2f_lo(kv.z), bf2f_hi(kv.z),
                                               bf2f_lo(kv.w), bf2f_hi(kv.w));
      *(float4*)&Vs[lane][c*8]   = make_float4(bf2f_lo(vv.x), bf2f_hi(vv.x),
                                               bf2f_lo(vv.y), bf2f_hi(vv.y));
      *(float4*)&Vs[lane][c*8+4] = make_float4(bf2f_lo(vv.z), bf2f_hi(vv.z),
                                               bf2f_lo(vv.w), bf2f_hi(vv.w));
    }
  }
  __syncthreads();
  if (!active) return;

  const float* rb = rel + ((size_t)head * 49 + lane) * 49;
  float s[49];
  float mx = -1e30f;
  #pragma unroll
  for (int m = 0; m < 49; m++) {
    float d = 0.f;
    #pragma unroll
    for (int c = 0; c < 8; c++) {
      float4 kk = *(const float4*)&Ks[m][c*4];
      d += q[c*4+0]*kk.x + q[c*4+1]*kk.y + q[c*4+2]*kk.z + q[c*4+3]*kk.w;
    }
    d += rb[m];
    s[m] = d;
    mx = fmaxf(mx, d);
  }
  float sum = 0.f;
  #pragma unroll
  for (int m = 0; m < 49; m++) { float e = __expf(s[m] - mx); s[m] = e; sum += e; }
  const float inv = 1.f / sum;

  float acc[32];
  #pragma unroll
  for (int d = 0; d < 32; d++) acc[d] = 0.f;
  #pragma unroll
  for (int m = 0; m < 49; m++) {
    const float p = s[m];
    #pragma unroll
    for (int c = 0; c < 8; c++) {
      float4 vv = *(const float4*)&Vs[m][c*4];
      acc[c*4+0] += p*vv.x; acc[c*4+1] += p*vv.y;
      acc[c*4+2] += p*vv.z; acc[c*4+3] += p*vv.w;
    }
  }
  uint4* op = (uint4*)(O + rowo);
  #pragma unroll
  for (int c = 0; c < 4; c++) {
    u32 w0 = (u32)f2bf(acc[c*8+0]*inv) | ((u32)f2bf(acc[c*8+1]*inv) << 16);
    u32 w1 = (u32)f2bf(acc[c*8+2]*inv) | ((u32)f2bf(acc[c*8+3]*inv) << 16);
    u32 w2 = (u32)f2bf(acc[c*8+4]*inv) | ((u32)f2bf(acc[c*8+5]*inv) << 16);
    u32 w3 = (u32)f2bf(acc[c*8+6]*inv) | ((u32)f2bf(acc[c*8+7]*inv) << 16);
    op[c] = make_uint4(w0, w1, w2, w3);
  }
}

// ---------- launch ----------
extern "C" void kernel_launch(void* const* d_in, const int* in_sizes, int n_in,
                              void* d_out, int out_size, void* d_ws, size_t ws_size,
                              hipStream_t stream) {
  (void)in_sizes; (void)n_in; (void)out_size; (void)ws_size;
  const float* x    = (const float*)d_in[0];
  const float* Wq   = (const float*)d_in[1];
  const float* bq   = (const float*)d_in[2];
  const float* Wk   = (const float*)d_in[3];
  const float* bk   = (const float*)d_in[4];
  const float* Wv   = (const float*)d_in[5];
  const float* bv   = (const float*)d_in[6];
  const float* Wp   = (const float*)d_in[7];
  const float* bp   = (const float*)d_in[8];
  const float* rel  = (const float*)d_in[9];
  const float* g1   = (const float*)d_in[10];
  const float* b1   = (const float*)d_in[11];
  const float* g2   = (const float*)d_in[12];
  const float* b2   = (const float*)d_in[13];
  const float* W1   = (const float*)d_in[14];
  const float* bfc1 = (const float*)d_in[15];
  const float* W2   = (const float*)d_in[16];
  const float* bfc2 = (const float*)d_in[17];
  float* out = (float*)d_out;

  // workspace layout (u16 units)
  u16* wQKV = (u16*)d_ws;                          // 1536*512
  u16* wWp  = wQKV + (size_t)1536*512;             // 512*512
  u16* wW1  = wWp  + (size_t)512*512;              // 2048*512
  u16* wW2  = wW1  + (size_t)2048*512;             // 512*2048
  float* bqkv = (float*)(wW2 + (size_t)512*2048);  // 1536 fp32
  u16* hbuf = (u16*)(bqkv + 1536);                 // M*512 (LN1 out; later LN2 out)
  u16* QKVb = hbuf + (size_t)Mm * Cc;              // M*1536 (later: MLP hidden part)
  u16* Obuf = QKVb + (size_t)Mm * 1536;            // M*512
  u16* x2bf = Obuf + (size_t)Mm * Cc;              // M*512 bf16 residual
  u16* hid  = QKVb;                                // M*2048 overlays QKVb+Obuf
  u16* h2   = hbuf;

  // weights -> bf16 transposed (QKV fused into 1536 rows)
  wcvt_k<<<(512*512)/256,  256, 0, stream>>>(Wq, wQKV,              512, 512);
  wcvt_k<<<(512*512)/256,  256, 0, stream>>>(Wk, wQKV + 512*512,    512, 512);
  wcvt_k<<<(512*512)/256,  256, 0, stream>>>(Wv, wQKV + 2*512*512,  512, 512);
  wcvt_k<<<(512*512)/256,  256, 0, stream>>>(Wp, wWp, 512, 512);
  wcvt_k<<<(512*2048)/256, 256, 0, stream>>>(W1, wW1, 512, 2048);
  wcvt_k<<<(512*2048)/256, 256, 0, stream>>>(W2, wW2, 2048, 512);
  bcat_k<<<6, 256, 0, stream>>>(bq, bk, bv, bqkv);

  // LN1
  ln_k<<<Mm/4, 256, 0, stream>>>(x, g1, b1, hbuf);

  // fused QKV projection: (M,1536), 392*12 blocks
  gemm_bt<0><<<392*12, 256, 0, stream>>>(hbuf, wQKV, bqkv, nullptr, QKVb,
                                         Mm, 1536, 512, 12);

  // attention
  attn_k<<<dim3(1024, 16), 64, 0, stream>>>(QKVb, rel, Obuf);

  // proj + residual(x fp32) -> x2 bf16
  gemm_bt<2><<<392*4, 256, 0, stream>>>(Obuf, wWp, bp, x, x2bf,
                                        Mm, 512, 512, 4);

  // LN2 (bf16 in)
  ln_bf_k<<<Mm/4, 256, 0, stream>>>(x2bf, g2, b2, h2);

  // MLP
  gemm_bt<1><<<392*16, 256, 0, stream>>>(h2, wW1, bfc1, nullptr, hid,
                                         Mm, 2048, 512, 16);
  gemm_bt<3><<<392*4, 256, 0, stream>>>(hid, wW2, bfc2, x2bf, out,
                                        Mm, 512, 2048, 4);
}

// Round 4
// 799.083 us; speedup vs baseline: 1.4100x; 1.1395x over previous
//
#include <hip/hip_runtime.h>

typedef unsigned short u16;
typedef unsigned int   u32;

using short8  = __attribute__((ext_vector_type(8))) short;
using floatx4 = __attribute__((ext_vector_type(4))) float;

// ---------- constants ----------
#define Bb   16
#define Hh   56
#define Ww   56
#define Cc   512
#define NHh  16
#define HDd  32
#define HIDh 2048
#define Ll   (Hh*Ww)          // 3136
#define Mm   (Bb*Ll)          // 50176
#define SCALE 0.17677669529663687f
#define CSTR 136              // GEMM C-tile LDS row stride (u16)
#define PSTR 72               // attn LDS row stride (u16): 144B = 16B-aligned

// ---------- helpers ----------
__device__ __forceinline__ u16 f2bf(float f) {
  union { float f; u32 u; } v; v.f = f;
  u32 r = (v.u + 0x7fffu + ((v.u >> 16) & 1u)) >> 16;
  return (u16)r;
}
__device__ __forceinline__ float bf2f(u16 u) {
  union { u32 u; float f; } v; v.u = ((u32)u) << 16; return v.f;
}
__device__ __forceinline__ float bf2f_lo(u32 u) {
  union { u32 u; float f; } v; v.u = u << 16; return v.f;
}
__device__ __forceinline__ float bf2f_hi(u32 u) {
  union { u32 u; float f; } v; v.u = u & 0xffff0000u; return v.f;
}
// gelu with A&S 7.1.26 erf (|err| < 1.5e-7): ~2x cheaper than libm erff.
__device__ __forceinline__ float gelu_f(float x) {
  const float z  = x * 0.70710678118654752f;
  const float az = fabsf(z);
  const float t  = __builtin_amdgcn_rcpf(fmaf(0.3275911f, az, 1.f));
  float p = fmaf(1.061405429f, t, -1.453152027f);
  p = fmaf(p, t, 1.421413741f);
  p = fmaf(p, t, -0.284496736f);
  p = fmaf(p, t, 0.254829592f);
  const float e = p * t * __expf(-z * z);     // 1 - erf(|z|)
  float erfz = 1.f - e;
  erfz = copysignf(erfz, z);
  return 0.5f * x * (1.f + erfz);
}
__device__ __forceinline__ void gld_lds16(const u16* g, u16* l) {
  __builtin_amdgcn_global_load_lds(
      (__attribute__((address_space(1))) void*)(void*)g,
      (__attribute__((address_space(3))) void*)(void*)l,
      16, 0, 0);
}

// ---------- weight convert+transpose: Wt[n][k] = bf16(W[k][n]) ----------
__global__ void wcvt_k(const float* __restrict__ W, u16* __restrict__ Wt,
                       int K, int N) {
  int idx = blockIdx.x * 256 + threadIdx.x;     // over N*K
  int n = idx / K;
  int k = idx - n * K;
  Wt[idx] = f2bf(W[(size_t)k * N + n]);
}

// ---------- concat 3 bias vectors (512 each) ----------
__global__ void bcat_k(const float* __restrict__ a, const float* __restrict__ b,
                       const float* __restrict__ c, float* __restrict__ o) {
  int i = blockIdx.x * 256 + threadIdx.x;   // 0..1535
  float v = (i < 512) ? a[i] : (i < 1024) ? b[i - 512] : c[i - 1024];
  o[i] = v;
}

// ---------- rel bias -> MFMA D-fragment layout, masks baked in ----------
// relL[(((h*4+mi)*4+nj)*64 + lane)*4 + reg] =
//   row = mi*16 + (lane>>4)*4 + reg, col = nj*16 + (lane&15)
//   col>=49 -> -1e30 (softmax zero), row>=49 -> 0 (discarded rows)
__global__ void relprep_k(const float* __restrict__ rel, float* __restrict__ relL) {
  int idx  = blockIdx.x * 256 + threadIdx.x;    // 0..65535
  int reg  = idx & 3;
  int lane = (idx >> 2) & 63;
  int frag = (idx >> 8) & 15;
  int h    = idx >> 12;
  int mi = frag >> 2, nj = frag & 3;
  int row = mi * 16 + (lane >> 4) * 4 + reg;
  int col = nj * 16 + (lane & 15);
  float v;
  if (col >= 49)      v = -1e30f;
  else if (row >= 49) v = 0.f;
  else                v = rel[((size_t)h * 49 + row) * 49 + col];
  relL[idx] = v;
}

// ---------- layernorm fp32 in -> bf16 out, one wave per row ----------
__global__ __launch_bounds__(256)
void ln_k(const float* __restrict__ x, const float* __restrict__ g,
          const float* __restrict__ b, u16* __restrict__ out) {
  const int row  = blockIdx.x * 4 + (threadIdx.x >> 6);
  const int lane = threadIdx.x & 63;
  const float* xr = x + (size_t)row * Cc + lane * 8;
  float4 v0 = *(const float4*)xr;
  float4 v1 = *(const float4*)(xr + 4);
  float s  = v0.x+v0.y+v0.z+v0.w + v1.x+v1.y+v1.z+v1.w;
  float s2 = v0.x*v0.x+v0.y*v0.y+v0.z*v0.z+v0.w*v0.w
           + v1.x*v1.x+v1.y*v1.y+v1.z*v1.z+v1.w*v1.w;
  #pragma unroll
  for (int off = 32; off >= 1; off >>= 1) {
    s  += __shfl_xor(s,  off);
    s2 += __shfl_xor(s2, off);
  }
  float mu  = s  * (1.f/512.f);
  float var = s2 * (1.f/512.f) - mu*mu;
  float rs  = rsqrtf(var + 1e-5f);
  float4 ga = *(const float4*)(g + lane*8);
  float4 gb = *(const float4*)(g + lane*8 + 4);
  float4 ba = *(const float4*)(b + lane*8);
  float4 bb = *(const float4*)(b + lane*8 + 4);
  float o0 = (v0.x-mu)*rs*ga.x + ba.x;
  float o1 = (v0.y-mu)*rs*ga.y + ba.y;
  float o2 = (v0.z-mu)*rs*ga.z + ba.z;
  float o3 = (v0.w-mu)*rs*ga.w + ba.w;
  float o4 = (v1.x-mu)*rs*gb.x + bb.x;
  float o5 = (v1.y-mu)*rs*gb.y + bb.y;
  float o6 = (v1.z-mu)*rs*gb.z + bb.z;
  float o7 = (v1.w-mu)*rs*gb.w + bb.w;
  u32 w0 = (u32)f2bf(o0) | ((u32)f2bf(o1) << 16);
  u32 w1 = (u32)f2bf(o2) | ((u32)f2bf(o3) << 16);
  u32 w2 = (u32)f2bf(o4) | ((u32)f2bf(o5) << 16);
  u32 w3 = (u32)f2bf(o6) | ((u32)f2bf(o7) << 16);
  *(uint4*)(out + (size_t)row * Cc + lane * 8) = make_uint4(w0, w1, w2, w3);
}

// ---------- layernorm bf16 in -> bf16 out ----------
__global__ __launch_bounds__(256)
void ln_bf_k(const u16* __restrict__ x, const float* __restrict__ g,
             const float* __restrict__ b, u16* __restrict__ out) {
  const int row  = blockIdx.x * 4 + (threadIdx.x >> 6);
  const int lane = threadIdx.x & 63;
  uint4 xv = *(const uint4*)(x + (size_t)row * Cc + lane * 8);
  float v[8];
  v[0]=bf2f_lo(xv.x); v[1]=bf2f_hi(xv.x); v[2]=bf2f_lo(xv.y); v[3]=bf2f_hi(xv.y);
  v[4]=bf2f_lo(xv.z); v[5]=bf2f_hi(xv.z); v[6]=bf2f_lo(xv.w); v[7]=bf2f_hi(xv.w);
  float s = 0.f, s2 = 0.f;
  #pragma unroll
  for (int i = 0; i < 8; i++) { s += v[i]; s2 += v[i]*v[i]; }
  #pragma unroll
  for (int off = 32; off >= 1; off >>= 1) {
    s  += __shfl_xor(s,  off);
    s2 += __shfl_xor(s2, off);
  }
  float mu  = s  * (1.f/512.f);
  float var = s2 * (1.f/512.f) - mu*mu;
  float rs  = rsqrtf(var + 1e-5f);
  float4 ga = *(const float4*)(g + lane*8);
  float4 gb = *(const float4*)(g + lane*8 + 4);
  float4 ba = *(const float4*)(b + lane*8);
  float4 bb = *(const float4*)(b + lane*8 + 4);
  float o[8];
  o[0]=(v[0]-mu)*rs*ga.x+ba.x; o[1]=(v[1]-mu)*rs*ga.y+ba.y;
  o[2]=(v[2]-mu)*rs*ga.z+ba.z; o[3]=(v[3]-mu)*rs*ga.w+ba.w;
  o[4]=(v[4]-mu)*rs*gb.x+bb.x; o[5]=(v[5]-mu)*rs*gb.y+bb.y;
  o[6]=(v[6]-mu)*rs*gb.z+bb.z; o[7]=(v[7]-mu)*rs*gb.w+bb.w;
  u32 w0 = (u32)f2bf(o[0]) | ((u32)f2bf(o[1]) << 16);
  u32 w1 = (u32)f2bf(o[2]) | ((u32)f2bf(o[3]) << 16);
  u32 w2 = (u32)f2bf(o[4]) | ((u32)f2bf(o[5]) << 16);
  u32 w3 = (u32)f2bf(o[6]) | ((u32)f2bf(o[7]) << 16);
  *(uint4*)(out + (size_t)row * Cc + lane * 8) = make_uint4(w0, w1, w2, w3);
}

// ---------- GEMM: out[M,N] = A[M,K](bf16) @ Bt[N,K](bf16)^T + bias ----------
// 128x128 tile, BK=32, 256 threads (4 waves, 2x2), XCD-aware swizzle.
// Double-buffered LDS + counted-wait single-barrier K-loop (round-3 verified).
// MODE 0: -> bf16   MODE 1: gelu -> bf16   MODE 2: +res(fp32) -> bf16
// MODE 3: +res(bf16) -> fp32 (direct stores)
template<int MODE>
__global__ __launch_bounds__(256, 4)
void gemm_bt(const u16* __restrict__ A, const u16* __restrict__ Bt,
             const float* __restrict__ bias, const void* __restrict__ res,
             void* __restrict__ outp, int M, int N, int K, int nbn) {
  (void)M;
  __shared__ __align__(16) u16 smem[128 * CSTR];   // 34816 B; aliases dbuf + C

  const int b   = blockIdx.x;
  const int xcd = b & 7;
  const int s   = b >> 3;
  const int mt  = (s / nbn) * 8 + xcd;
  const int nt  = s - (s / nbn) * nbn;
  const int m0  = mt * 128;
  const int n0  = nt * 128;

  const int tid  = threadIdx.x;
  const int lane = tid & 63;
  const int wave = tid >> 6;
  const int wm = (wave >> 1) * 64;
  const int wn = (wave & 1) * 64;
  const int quad = lane >> 4;
  const int l16  = lane & 15;

  floatx4 acc[4][4];
  #pragma unroll
  for (int i = 0; i < 4; i++)
    #pragma unroll
    for (int j = 0; j < 4; j++) acc[i][j] = (floatx4)0.f;

  const int r0  = tid >> 2;
  const int cc0 = (((tid & 3) ^ ((r0 >> 1) & 3)) * 8);   // XOR-swizzled k-offset
  const u16* Ag = A  + (size_t)m0 * K;
  const u16* Bg = Bt + (size_t)n0 * K;

  const int fswz = (l16 >> 1) & 3;
  const int aoff = (quad ^ fswz) * 8;

#define STG(kk, bufo) do {                                                        \
    gld_lds16(Ag + (size_t)r0        * K + (kk) + cc0, &smem[(bufo) + wave * 512]);        \
    gld_lds16(Ag + (size_t)(r0 + 64) * K + (kk) + cc0, &smem[(bufo) + 2048 + wave * 512]); \
    gld_lds16(Bg + (size_t)r0        * K + (kk) + cc0, &smem[(bufo) + 4096 + wave * 512]); \
    gld_lds16(Bg + (size_t)(r0 + 64) * K + (kk) + cc0, &smem[(bufo) + 6144 + wave * 512]); \
  } while (0)

  STG(0, 0);
  asm volatile("s_waitcnt vmcnt(0)" ::: "memory");
  __builtin_amdgcn_s_barrier();

  for (int k0 = 0; k0 < K; k0 += 32) {
    const int bufo = ((k0 >> 5) & 1) * 8192;
    if (k0 + 32 < K) STG(k0 + 32, bufo ^ 8192);
    const u16* As = &smem[bufo];
    const u16* Bs = &smem[bufo + 4096];
    short8 af[4], bf[4];
    #pragma unroll
    for (int mi = 0; mi < 4; mi++)
      af[mi] = *(const short8*)&As[(wm + mi*16 + l16) * 32 + aoff];
    #pragma unroll
    for (int ni = 0; ni < 4; ni++)
      bf[ni] = *(const short8*)&Bs[(wn + ni*16 + l16) * 32 + aoff];
    #pragma unroll
    for (int mi = 0; mi < 4; mi++)
      #pragma unroll
      for (int ni = 0; ni < 4; ni++)
        acc[mi][ni] = __builtin_amdgcn_mfma_f32_16x16x32_bf16(
            af[mi], bf[ni], acc[mi][ni], 0, 0, 0);
    asm volatile("s_waitcnt vmcnt(0)" ::: "memory");   // t+1 loads landed
    __builtin_amdgcn_s_barrier();
  }
#undef STG

  if (MODE == 3) {
    const int mrow = m0 + wm + quad * 4;
    const int ncol = n0 + wn + l16;
    #pragma unroll
    for (int ni = 0; ni < 4; ni++) {
      const int n = ncol + ni * 16;
      const float bv = bias[n];
      #pragma unroll
      for (int mi = 0; mi < 4; mi++)
        #pragma unroll
        for (int r = 0; r < 4; r++) {
          const size_t idx = (size_t)(mrow + mi * 16 + r) * N + n;
          ((float*)outp)[idx] = acc[mi][ni][r] + bv + bf2f(((const u16*)res)[idx]);
        }
    }
  } else {
    #pragma unroll
    for (int ni = 0; ni < 4; ni++) {
      const int col = wn + ni * 16 + l16;
      const float bv = bias[n0 + col];
      #pragma unroll
      for (int mi = 0; mi < 4; mi++)
        #pragma unroll
        for (int r = 0; r < 4; r++) {
          float v = acc[mi][ni][r] + bv;
          if (MODE == 1) v = gelu_f(v);
          smem[(wm + mi * 16 + quad * 4 + r) * CSTR + col] = f2bf(v);
        }
    }
    __syncthreads();
    const int trow = tid >> 4;            // 0..15
    const int tcol = (tid & 15) * 8;      // u16 col
    #pragma unroll
    for (int it = 0; it < 8; it++) {
      const int row = it * 16 + trow;
      uint4 w = *(const uint4*)&smem[row * CSTR + tcol];
      const size_t gi = (size_t)(m0 + row) * N + n0 + tcol;
      if (MODE == 2) {
        const float* rp = (const float*)res + gi;
        float4 ra = *(const float4*)rp;
        float4 rb = *(const float4*)(rp + 4);
        u32 w0 = (u32)f2bf(bf2f_lo(w.x) + ra.x) | ((u32)f2bf(bf2f_hi(w.x) + ra.y) << 16);
        u32 w1 = (u32)f2bf(bf2f_lo(w.y) + ra.z) | ((u32)f2bf(bf2f_hi(w.y) + ra.w) << 16);
        u32 w2 = (u32)f2bf(bf2f_lo(w.z) + rb.x) | ((u32)f2bf(bf2f_hi(w.z) + rb.y) << 16);
        u32 w3 = (u32)f2bf(bf2f_lo(w.w) + rb.z) | ((u32)f2bf(bf2f_hi(w.w) + rb.w) << 16);
        *(uint4*)((u16*)outp + gi) = make_uint4(w0, w1, w2, w3);
      } else {
        *(uint4*)((u16*)outp + gi) = w;
      }
    }
  }
}

// ---------- MFMA windowed attention: one wave per (window, head) ----------
// QKV interleaved bf16 (M, 1536): [Q 512 | K 512 | V 512]; out (M,512) bf16.
// 4 waves/block (4 heads of one window). 49 padded to 64 via row-clamp;
// padding columns masked to -1e30 in relL (baked by relprep_k) -> P == 0.
// Fragment conventions (verified by gemm_bt): A-frag row=l16, k=quad*8;
// B-frag "row" = output col; C/D col=lane&15, row=(lane>>4)*4+reg.
__global__ __launch_bounds__(256, 3)
void attn_k(const u16* __restrict__ QKV, const float* __restrict__ relL,
            u16* __restrict__ O) {
  __shared__ __align__(16) u16 Vt[4][32][PSTR];    // V^T per wave
  __shared__ __align__(16) u16 Pl[4][49 * PSTR];   // P, then O bounce

  const int tid  = threadIdx.x;
  const int wave = tid >> 6;
  const int lane = tid & 63;
  const int quad = lane >> 4;
  const int l16  = lane & 15;

  const int win  = blockIdx.x >> 2;                // 0..1023
  const int head = ((blockIdx.x & 3) << 2) + wave; // 0..15
  const int b    = win >> 6;
  const int wh   = (win >> 3) & 7;
  const int ww   = win & 7;
  const int base_l = b * Ll + (wh * 7) * Ww + ww * 7;

  // ---- stage V^T into LDS (all 64 lanes; pad rows k>=49 zeroed) ----
  u32 vw[16];
  #pragma unroll
  for (int i = 0; i < 16; i++) vw[i] = 0;
  const int lc = lane < 49 ? lane : 48;
  const size_t grl = (size_t)base_l + (lc / 7) * 56 + (lc % 7);
  if (lane < 49) {
    const uint4* vp = (const uint4*)(QKV + grl * 1536 + 1024 + head * HDd);
    uint4 a0 = vp[0], a1 = vp[1], a2 = vp[2], a3 = vp[3];
    vw[0]=a0.x;  vw[1]=a0.y;  vw[2]=a0.z;  vw[3]=a0.w;
    vw[4]=a1.x;  vw[5]=a1.y;  vw[6]=a1.z;  vw[7]=a1.w;
    vw[8]=a2.x;  vw[9]=a2.y;  vw[10]=a2.z; vw[11]=a2.w;
    vw[12]=a3.x; vw[13]=a3.y; vw[14]=a3.z; vw[15]=a3.w;
  }
  {
    u16* vtb = &Vt[wave][0][lane];
    #pragma unroll
    for (int c = 0; c < 32; c++)
      vtb[c * PSTR] = (u16)(vw[c >> 1] >> ((c & 1) << 4));
  }

  // ---- Q/K fragments direct from global (row-clamped) ----
  size_t gr16[4];
  #pragma unroll
  for (int t = 0; t < 4; t++) {
    int r = t * 16 + l16; if (r > 48) r = 48;
    gr16[t] = (size_t)base_l + (r / 7) * 56 + (r % 7);
  }
  short8 qf[4], kf[4];
  #pragma unroll
  for (int t = 0; t < 4; t++) {
    qf[t] = *(const short8*)(QKV + gr16[t] * 1536 + head * HDd + quad * 8);
    kf[t] = *(const short8*)(QKV + gr16[t] * 1536 + 512 + head * HDd + quad * 8);
  }

  // ---- QK^T: 16 MFMA ----
  floatx4 acc[4][4];
  #pragma unroll
  for (int mi = 0; mi < 4; mi++)
    #pragma unroll
    for (int nj = 0; nj < 4; nj++) acc[mi][nj] = (floatx4)0.f;
  #pragma unroll
  for (int mi = 0; mi < 4; mi++)
    #pragma unroll
    for (int nj = 0; nj < 4; nj++)
      acc[mi][nj] = __builtin_amdgcn_mfma_f32_16x16x32_bf16(
          qf[mi], kf[nj], acc[mi][nj], 0, 0, 0);

  // ---- scale + rel bias (mask baked in) ----
  const float* rlb = relL + ((size_t)head << 12) + lane * 4;
  #pragma unroll
  for (int mi = 0; mi < 4; mi++)
    #pragma unroll
    for (int nj = 0; nj < 4; nj++) {
      float4 rl = *(const float4*)(rlb + ((mi * 4 + nj) << 8));
      acc[mi][nj][0] = fmaf(acc[mi][nj][0], SCALE, rl.x);
      acc[mi][nj][1] = fmaf(acc[mi][nj][1], SCALE, rl.y);
      acc[mi][nj][2] = fmaf(acc[mi][nj][2], SCALE, rl.z);
      acc[mi][nj][3] = fmaf(acc[mi][nj][3], SCALE, rl.w);
    }

  // ---- row softmax (rows live in 16-lane groups; xor 1,2,4,8) ----
  float sums[4][4];
  #pragma unroll
  for (int mi = 0; mi < 4; mi++)
    #pragma unroll
    for (int r = 0; r < 4; r++) {
      float mx = fmaxf(fmaxf(acc[mi][0][r], acc[mi][1][r]),
                       fmaxf(acc[mi][2][r], acc[mi][3][r]));
      #pragma unroll
      for (int off = 8; off >= 1; off >>= 1)
        mx = fmaxf(mx, __shfl_xor(mx, off));
      float sm = 0.f;
      #pragma unroll
      for (int nj = 0; nj < 4; nj++) {
        float e = __expf(acc[mi][nj][r] - mx);
        acc[mi][nj][r] = e;
        sm += e;
      }
      #pragma unroll
      for (int off = 8; off >= 1; off >>= 1)
        sm += __shfl_xor(sm, off);
      sums[mi][r] = sm;
    }

  // ---- P -> bf16 -> LDS (rows<49; row 48 only from mi=3,quad=0,r=0) ----
  u16* Pw = Pl[wave];
  {
    u16* pb = Pw + (quad * 4) * PSTR + l16;
    #pragma unroll
    for (int mi = 0; mi < 3; mi++)
      #pragma unroll
      for (int r = 0; r < 4; r++)
        #pragma unroll
        for (int nj = 0; nj < 4; nj++)
          pb[(mi * 16 + r) * PSTR + nj * 16] = f2bf(acc[mi][nj][r]);
    if (quad == 0) {
      #pragma unroll
      for (int nj = 0; nj < 4; nj++)
        pb[48 * PSTR + nj * 16] = f2bf(acc[3][nj][0]);
    }
  }
  asm volatile("s_waitcnt lgkmcnt(0)" ::: "memory");

  // ---- PV: 16 MFMA (A = P rows, B = V cols via Vt) ----
  floatx4 pv[4][2];
  #pragma unroll
  for (int mi = 0; mi < 4; mi++)
    #pragma unroll
    for (int nj = 0; nj < 2; nj++) pv[mi][nj] = (floatx4)0.f;
  #pragma unroll
  for (int ks = 0; ks < 2; ks++) {
    short8 pf[4], vf[2];
    #pragma unroll
    for (int mi = 0; mi < 4; mi++) {
      const int pr = (mi < 3) ? (mi * 16 + l16) : 48;
      pf[mi] = *(const short8*)&Pw[pr * PSTR + ks * 32 + quad * 8];
    }
    #pragma unroll
    for (int nj = 0; nj < 2; nj++)
      vf[nj] = *(const short8*)&Vt[wave][nj * 16 + l16][ks * 32 + quad * 8];
    #pragma unroll
    for (int mi = 0; mi < 4; mi++)
      #pragma unroll
      for (int nj = 0; nj < 2; nj++)
        pv[mi][nj] = __builtin_amdgcn_mfma_f32_16x16x32_bf16(
            pf[mi], vf[nj], pv[mi][nj], 0, 0, 0);
  }

  // ---- O = pv/sum -> LDS bounce (reuse P buffer) -> coalesced store ----
  asm volatile("s_waitcnt lgkmcnt(0)" ::: "memory");
  {
    u16* ob = Pw + (quad * 4) * PSTR + l16;
    #pragma unroll
    for (int mi = 0; mi < 3; mi++)
      #pragma unroll
      for (int r = 0; r < 4; r++) {
        const float inv = __builtin_amdgcn_rcpf(sums[mi][r]);
        ob[(mi * 16 + r) * PSTR +  0] = f2bf(pv[mi][0][r] * inv);
        ob[(mi * 16 + r) * PSTR + 16] = f2bf(pv[mi][1][r] * inv);
      }
    if (quad == 0) {
      const float inv = __builtin_amdgcn_rcpf(sums[3][0]);
      ob[48 * PSTR +  0] = f2bf(pv[3][0][0] * inv);
      ob[48 * PSTR + 16] = f2bf(pv[3][1][0] * inv);
    }
  }
  asm volatile("s_waitcnt lgkmcnt(0)" ::: "memory");
  if (lane < 49) {
    const uint4* orow = (const uint4*)&Pw[lane * PSTR];
    uint4* op = (uint4*)(O + grl * 512 + head * HDd);
    op[0] = orow[0]; op[1] = orow[1]; op[2] = orow[2]; op[3] = orow[3];
  }
}

// ---------- launch ----------
extern "C" void kernel_launch(void* const* d_in, const int* in_sizes, int n_in,
                              void* d_out, int out_size, void* d_ws, size_t ws_size,
                              hipStream_t stream) {
  (void)in_sizes; (void)n_in; (void)out_size; (void)ws_size;
  const float* x    = (const float*)d_in[0];
  const float* Wq   = (const float*)d_in[1];
  const float* bq   = (const float*)d_in[2];
  const float* Wk   = (const float*)d_in[3];
  const float* bk   = (const float*)d_in[4];
  const float* Wv   = (const float*)d_in[5];
  const float* bv   = (const float*)d_in[6];
  const float* Wp   = (const float*)d_in[7];
  const float* bp   = (const float*)d_in[8];
  const float* rel  = (const float*)d_in[9];
  const float* g1   = (const float*)d_in[10];
  const float* b1   = (const float*)d_in[11];
  const float* g2   = (const float*)d_in[12];
  const float* b2   = (const float*)d_in[13];
  const float* W1   = (const float*)d_in[14];
  const float* bfc1 = (const float*)d_in[15];
  const float* W2   = (const float*)d_in[16];
  const float* bfc2 = (const float*)d_in[17];
  float* out = (float*)d_out;

  // workspace layout (u16 units)
  u16* wQKV = (u16*)d_ws;                          // 1536*512
  u16* wWp  = wQKV + (size_t)1536*512;             // 512*512
  u16* wW1  = wWp  + (size_t)512*512;              // 2048*512
  u16* wW2  = wW1  + (size_t)2048*512;             // 512*2048
  float* bqkv = (float*)(wW2 + (size_t)512*2048);  // 1536 fp32
  float* relL = bqkv + 1536;                       // 65536 fp32 (256 KB)
  u16* hbuf = (u16*)(relL + 65536);                // M*512 (LN1 out; later LN2 out)
  u16* QKVb = hbuf + (size_t)Mm * Cc;              // M*1536 (later: MLP hidden part)
  u16* Obuf = QKVb + (size_t)Mm * 1536;            // M*512
  u16* x2bf = Obuf + (size_t)Mm * Cc;              // M*512 bf16 residual
  u16* hid  = QKVb;                                // M*2048 overlays QKVb+Obuf
  u16* h2   = hbuf;

  // weights -> bf16 transposed (QKV fused into 1536 rows)
  wcvt_k<<<(512*512)/256,  256, 0, stream>>>(Wq, wQKV,              512, 512);
  wcvt_k<<<(512*512)/256,  256, 0, stream>>>(Wk, wQKV + 512*512,    512, 512);
  wcvt_k<<<(512*512)/256,  256, 0, stream>>>(Wv, wQKV + 2*512*512,  512, 512);
  wcvt_k<<<(512*512)/256,  256, 0, stream>>>(Wp, wWp, 512, 512);
  wcvt_k<<<(512*2048)/256, 256, 0, stream>>>(W1, wW1, 512, 2048);
  wcvt_k<<<(512*2048)/256, 256, 0, stream>>>(W2, wW2, 2048, 512);
  bcat_k<<<6, 256, 0, stream>>>(bq, bk, bv, bqkv);
  relprep_k<<<65536/256, 256, 0, stream>>>(rel, relL);

  // LN1
  ln_k<<<Mm/4, 256, 0, stream>>>(x, g1, b1, hbuf);

  // fused QKV projection: (M,1536), 392*12 blocks
  gemm_bt<0><<<392*12, 256, 0, stream>>>(hbuf, wQKV, bqkv, nullptr, QKVb,
                                         Mm, 1536, 512, 12);

  // attention (MFMA): 4096 blocks x 256 threads, 4 window-heads/block
  attn_k<<<4096, 256, 0, stream>>>(QKVb, relL, Obuf);

  // proj + residual(x fp32) -> x2 bf16
  gemm_bt<2><<<392*4, 256, 0, stream>>>(Obuf, wWp, bp, x, x2bf,
                                        Mm, 512, 512, 4);

  // LN2 (bf16 in)
  ln_bf_k<<<Mm/4, 256, 0, stream>>>(x2bf, g2, b2, h2);

  // MLP
  gemm_bt<1><<<392*16, 256, 0, stream>>>(h2, wW1, bfc1, nullptr, hid,
                                         Mm, 2048, 512, 16);
  gemm_bt<3><<<392*4, 256, 0, stream>>>(hid, wW2, bfc2, x2bf, out,
                                        Mm, 512, 2048, 4);
}

// Round 5
// 772.763 us; speedup vs baseline: 1.4580x; 1.0341x over previous
//
#include <hip/hip_runtime.h>

typedef unsigned short u16;
typedef unsigned int   u32;

using short8  = __attribute__((ext_vector_type(8))) short;
using floatx4 = __attribute__((ext_vector_type(4))) float;

// ---------- constants ----------
#define Bb   16
#define Hh   56
#define Ww   56
#define Cc   512
#define NHh  16
#define HDd  32
#define HIDh 2048
#define Ll   (Hh*Ww)          // 3136
#define Mm   (Bb*Ll)          // 50176
#define SCALE 0.17677669529663687f
#define CSTR 136              // GEMM C-tile LDS row stride (u16)
#define PSTR 72               // attn LDS row stride (u16): 144B = 16B-aligned

// ---------- helpers ----------
__device__ __forceinline__ u16 f2bf(float f) {
  union { float f; u32 u; } v; v.f = f;
  u32 r = (v.u + 0x7fffu + ((v.u >> 16) & 1u)) >> 16;
  return (u16)r;
}
__device__ __forceinline__ float bf2f(u16 u) {
  union { u32 u; float f; } v; v.u = ((u32)u) << 16; return v.f;
}
__device__ __forceinline__ float bf2f_lo(u32 u) {
  union { u32 u; float f; } v; v.u = u << 16; return v.f;
}
__device__ __forceinline__ float bf2f_hi(u32 u) {
  union { u32 u; float f; } v; v.u = u & 0xffff0000u; return v.f;
}
// gelu with A&S 7.1.26 erf (|err| < 1.5e-7): ~2x cheaper than libm erff.
__device__ __forceinline__ float gelu_f(float x) {
  const float z  = x * 0.70710678118654752f;
  const float az = fabsf(z);
  const float t  = __builtin_amdgcn_rcpf(fmaf(0.3275911f, az, 1.f));
  float p = fmaf(1.061405429f, t, -1.453152027f);
  p = fmaf(p, t, 1.421413741f);
  p = fmaf(p, t, -0.284496736f);
  p = fmaf(p, t, 0.254829592f);
  const float e = p * t * __expf(-z * z);     // 1 - erf(|z|)
  float erfz = 1.f - e;
  erfz = copysignf(erfz, z);
  return 0.5f * x * (1.f + erfz);
}
__device__ __forceinline__ void gld_lds16(const u16* g, u16* l) {
  __builtin_amdgcn_global_load_lds(
      (__attribute__((address_space(1))) void*)(void*)g,
      (__attribute__((address_space(3))) void*)(void*)l,
      16, 0, 0);
}

// ---------- weight convert+transpose: Wt[n][k] = bf16(W[k][n]) ----------
__global__ void wcvt_k(const float* __restrict__ W, u16* __restrict__ Wt,
                       int K, int N) {
  int idx = blockIdx.x * 256 + threadIdx.x;     // over N*K
  int n = idx / K;
  int k = idx - n * K;
  Wt[idx] = f2bf(W[(size_t)k * N + n]);
}

// ---------- concat 3 bias vectors (512 each) ----------
__global__ void bcat_k(const float* __restrict__ a, const float* __restrict__ b,
                       const float* __restrict__ c, float* __restrict__ o) {
  int i = blockIdx.x * 256 + threadIdx.x;   // 0..1535
  float v = (i < 512) ? a[i] : (i < 1024) ? b[i - 512] : c[i - 1024];
  o[i] = v;
}

// ---------- rel bias -> MFMA D-fragment layout, masks baked in ----------
// relL[(((h*4+mi)*4+nj)*64 + lane)*4 + reg] =
//   row = mi*16 + (lane>>4)*4 + reg, col = nj*16 + (lane&15)
//   col>=49 -> -1e30 (softmax zero), row>=49 -> 0 (discarded rows)
__global__ void relprep_k(const float* __restrict__ rel, float* __restrict__ relL) {
  int idx  = blockIdx.x * 256 + threadIdx.x;    // 0..65535
  int reg  = idx & 3;
  int lane = (idx >> 2) & 63;
  int frag = (idx >> 8) & 15;
  int h    = idx >> 12;
  int mi = frag >> 2, nj = frag & 3;
  int row = mi * 16 + (lane >> 4) * 4 + reg;
  int col = nj * 16 + (lane & 15);
  float v;
  if (col >= 49)      v = -1e30f;
  else if (row >= 49) v = 0.f;
  else                v = rel[((size_t)h * 49 + row) * 49 + col];
  relL[idx] = v;
}

// ---------- layernorm fp32 in -> bf16 out, one wave per row ----------
__global__ __launch_bounds__(256)
void ln_k(const float* __restrict__ x, const float* __restrict__ g,
          const float* __restrict__ b, u16* __restrict__ out) {
  const int row  = blockIdx.x * 4 + (threadIdx.x >> 6);
  const int lane = threadIdx.x & 63;
  const float* xr = x + (size_t)row * Cc + lane * 8;
  float4 v0 = *(const float4*)xr;
  float4 v1 = *(const float4*)(xr + 4);
  float s  = v0.x+v0.y+v0.z+v0.w + v1.x+v1.y+v1.z+v1.w;
  float s2 = v0.x*v0.x+v0.y*v0.y+v0.z*v0.z+v0.w*v0.w
           + v1.x*v1.x+v1.y*v1.y+v1.z*v1.z+v1.w*v1.w;
  #pragma unroll
  for (int off = 32; off >= 1; off >>= 1) {
    s  += __shfl_xor(s,  off);
    s2 += __shfl_xor(s2, off);
  }
  float mu  = s  * (1.f/512.f);
  float var = s2 * (1.f/512.f) - mu*mu;
  float rs  = rsqrtf(var + 1e-5f);
  float4 ga = *(const float4*)(g + lane*8);
  float4 gb = *(const float4*)(g + lane*8 + 4);
  float4 ba = *(const float4*)(b + lane*8);
  float4 bb = *(const float4*)(b + lane*8 + 4);
  float o0 = (v0.x-mu)*rs*ga.x + ba.x;
  float o1 = (v0.y-mu)*rs*ga.y + ba.y;
  float o2 = (v0.z-mu)*rs*ga.z + ba.z;
  float o3 = (v0.w-mu)*rs*ga.w + ba.w;
  float o4 = (v1.x-mu)*rs*gb.x + bb.x;
  float o5 = (v1.y-mu)*rs*gb.y + bb.y;
  float o6 = (v1.z-mu)*rs*gb.z + bb.z;
  float o7 = (v1.w-mu)*rs*gb.w + bb.w;
  u32 w0 = (u32)f2bf(o0) | ((u32)f2bf(o1) << 16);
  u32 w1 = (u32)f2bf(o2) | ((u32)f2bf(o3) << 16);
  u32 w2 = (u32)f2bf(o4) | ((u32)f2bf(o5) << 16);
  u32 w3 = (u32)f2bf(o6) | ((u32)f2bf(o7) << 16);
  *(uint4*)(out + (size_t)row * Cc + lane * 8) = make_uint4(w0, w1, w2, w3);
}

// ---------- layernorm bf16 in -> bf16 out ----------
__global__ __launch_bounds__(256)
void ln_bf_k(const u16* __restrict__ x, const float* __restrict__ g,
             const float* __restrict__ b, u16* __restrict__ out) {
  const int row  = blockIdx.x * 4 + (threadIdx.x >> 6);
  const int lane = threadIdx.x & 63;
  uint4 xv = *(const uint4*)(x + (size_t)row * Cc + lane * 8);
  float v[8];
  v[0]=bf2f_lo(xv.x); v[1]=bf2f_hi(xv.x); v[2]=bf2f_lo(xv.y); v[3]=bf2f_hi(xv.y);
  v[4]=bf2f_lo(xv.z); v[5]=bf2f_hi(xv.z); v[6]=bf2f_lo(xv.w); v[7]=bf2f_hi(xv.w);
  float s = 0.f, s2 = 0.f;
  #pragma unroll
  for (int i = 0; i < 8; i++) { s += v[i]; s2 += v[i]*v[i]; }
  #pragma unroll
  for (int off = 32; off >= 1; off >>= 1) {
    s  += __shfl_xor(s,  off);
    s2 += __shfl_xor(s2, off);
  }
  float mu  = s  * (1.f/512.f);
  float var = s2 * (1.f/512.f) - mu*mu;
  float rs  = rsqrtf(var + 1e-5f);
  float4 ga = *(const float4*)(g + lane*8);
  float4 gb = *(const float4*)(g + lane*8 + 4);
  float4 ba = *(const float4*)(b + lane*8);
  float4 bb = *(const float4*)(b + lane*8 + 4);
  float o[8];
  o[0]=(v[0]-mu)*rs*ga.x+ba.x; o[1]=(v[1]-mu)*rs*ga.y+ba.y;
  o[2]=(v[2]-mu)*rs*ga.z+ba.z; o[3]=(v[3]-mu)*rs*ga.w+ba.w;
  o[4]=(v[4]-mu)*rs*gb.x+bb.x; o[5]=(v[5]-mu)*rs*gb.y+bb.y;
  o[6]=(v[6]-mu)*rs*gb.z+bb.z; o[7]=(v[7]-mu)*rs*gb.w+bb.w;
  u32 w0 = (u32)f2bf(o[0]) | ((u32)f2bf(o[1]) << 16);
  u32 w1 = (u32)f2bf(o[2]) | ((u32)f2bf(o[3]) << 16);
  u32 w2 = (u32)f2bf(o[4]) | ((u32)f2bf(o[5]) << 16);
  u32 w3 = (u32)f2bf(o[6]) | ((u32)f2bf(o[7]) << 16);
  *(uint4*)(out + (size_t)row * Cc + lane * 8) = make_uint4(w0, w1, w2, w3);
}

// ---------- GEMM: out[M,N] = A[M,K](bf16) @ Bt[N,K](bf16)^T + bias ----------
// 128x128 tile, BK=32, 256 threads (4 waves, 2x2), XCD-aware swizzle.
// TRIPLE-buffered LDS (3 x 16 KB) with depth-2 prefetch + counted vmcnt:
// step t stages tile t+2 into buf[(t+2)%3], computes buf[t%3], and ends with
// vmcnt(4) (drain t+1's 4 loads, keep t+2's 4 in flight) — never 0 mid-loop.
// Each load now gets ~2 full steps to cover ~900cyc HBM latency (round-4
// counters: MfmaUtil 24.5% == stall-dominated with depth-1 drain).
// Stage target buf[(t+2)%3] == buffer computed at step t-1; the end-of-step
// barrier of t-1 guarantees all waves finished reading it (same invariant
// as the verified double-buffer version). LDS 49152 B -> 3 blocks/CU.
// MODE 0: -> bf16   MODE 1: gelu -> bf16   MODE 2: +res(fp32) -> bf16
// MODE 3: +res(bf16) -> fp32 (direct stores)
template<int MODE>
__global__ __launch_bounds__(256, 3)
void gemm_bt(const u16* __restrict__ A, const u16* __restrict__ Bt,
             const float* __restrict__ bias, const void* __restrict__ res,
             void* __restrict__ outp, int M, int N, int K, int nbn) {
  (void)M;
  __shared__ __align__(16) u16 smem[24576];   // 49152 B; 3 bufs; aliases C-stage

  const int b   = blockIdx.x;
  const int xcd = b & 7;
  const int s   = b >> 3;
  const int mt  = (s / nbn) * 8 + xcd;
  const int nt  = s - (s / nbn) * nbn;
  const int m0  = mt * 128;
  const int n0  = nt * 128;

  const int tid  = threadIdx.x;
  const int lane = tid & 63;
  const int wave = tid >> 6;
  const int wm = (wave >> 1) * 64;
  const int wn = (wave & 1) * 64;
  const int quad = lane >> 4;
  const int l16  = lane & 15;

  floatx4 acc[4][4];
  #pragma unroll
  for (int i = 0; i < 4; i++)
    #pragma unroll
    for (int j = 0; j < 4; j++) acc[i][j] = (floatx4)0.f;

  const int r0  = tid >> 2;
  const int cc0 = (((tid & 3) ^ ((r0 >> 1) & 3)) * 8);   // XOR-swizzled k-offset
  const u16* Ag = A  + (size_t)m0 * K;
  const u16* Bg = Bt + (size_t)n0 * K;

  const int fswz = (l16 >> 1) & 3;
  const int aoff = (quad ^ fswz) * 8;

  // buffer layout (u16): buf i at i*8192 = [A 4096 | B 4096]
#define STG(kk, bufo) do {                                                        \
    gld_lds16(Ag + (size_t)r0        * K + (kk) + cc0, &smem[(bufo) + wave * 512]);        \
    gld_lds16(Ag + (size_t)(r0 + 64) * K + (kk) + cc0, &smem[(bufo) + 2048 + wave * 512]); \
    gld_lds16(Bg + (size_t)r0        * K + (kk) + cc0, &smem[(bufo) + 4096 + wave * 512]); \
    gld_lds16(Bg + (size_t)(r0 + 64) * K + (kk) + cc0, &smem[(bufo) + 6144 + wave * 512]); \
  } while (0)

  // prologue: stage tiles 0 and 1 (K >= 512 always => nT >= 16)
  STG(0, 0);
  STG(32, 8192);
  asm volatile("s_waitcnt vmcnt(4)" ::: "memory");   // tile 0 landed
  __builtin_amdgcn_s_barrier();

  int bc = 0;        // compute-buffer offset (t   % 3)
  int bs = 16384;    // stage-buffer offset   (t+2 % 3)
  for (int k0 = 0; k0 < K; k0 += 32) {
    if (k0 + 64 < K) STG(k0 + 64, bs);
    const u16* As = &smem[bc];
    const u16* Bs = &smem[bc + 4096];
    short8 af[4], bf[4];
    #pragma unroll
    for (int mi = 0; mi < 4; mi++)
      af[mi] = *(const short8*)&As[(wm + mi*16 + l16) * 32 + aoff];
    #pragma unroll
    for (int ni = 0; ni < 4; ni++)
      bf[ni] = *(const short8*)&Bs[(wn + ni*16 + l16) * 32 + aoff];
    #pragma unroll
    for (int mi = 0; mi < 4; mi++)
      #pragma unroll
      for (int ni = 0; ni < 4; ni++)
        acc[mi][ni] = __builtin_amdgcn_mfma_f32_16x16x32_bf16(
            af[mi], bf[ni], acc[mi][ni], 0, 0, 0);
    if (k0 + 64 < K) {
      asm volatile("s_waitcnt vmcnt(4)" ::: "memory");   // t+1 landed, t+2 in flight
    } else if (k0 + 32 < K) {
      asm volatile("s_waitcnt vmcnt(0)" ::: "memory");   // tail: drain last tile
    }
    __builtin_amdgcn_s_barrier();
    bc = (bc == 16384) ? 0 : bc + 8192;
    bs = (bs == 16384) ? 0 : bs + 8192;
  }
#undef STG

  if (MODE == 3) {
    const int mrow = m0 + wm + quad * 4;
    const int ncol = n0 + wn + l16;
    #pragma unroll
    for (int ni = 0; ni < 4; ni++) {
      const int n = ncol + ni * 16;
      const float bv = bias[n];
      #pragma unroll
      for (int mi = 0; mi < 4; mi++)
        #pragma unroll
        for (int r = 0; r < 4; r++) {
          const size_t idx = (size_t)(mrow + mi * 16 + r) * N + n;
          ((float*)outp)[idx] = acc[mi][ni][r] + bv + bf2f(((const u16*)res)[idx]);
        }
    }
  } else {
    #pragma unroll
    for (int ni = 0; ni < 4; ni++) {
      const int col = wn + ni * 16 + l16;
      const float bv = bias[n0 + col];
      #pragma unroll
      for (int mi = 0; mi < 4; mi++)
        #pragma unroll
        for (int r = 0; r < 4; r++) {
          float v = acc[mi][ni][r] + bv;
          if (MODE == 1) v = gelu_f(v);
          smem[(wm + mi * 16 + quad * 4 + r) * CSTR + col] = f2bf(v);
        }
    }
    __syncthreads();
    const int trow = tid >> 4;            // 0..15
    const int tcol = (tid & 15) * 8;      // u16 col
    #pragma unroll
    for (int it = 0; it < 8; it++) {
      const int row = it * 16 + trow;
      uint4 w = *(const uint4*)&smem[row * CSTR + tcol];
      const size_t gi = (size_t)(m0 + row) * N + n0 + tcol;
      if (MODE == 2) {
        const float* rp = (const float*)res + gi;
        float4 ra = *(const float4*)rp;
        float4 rb = *(const float4*)(rp + 4);
        u32 w0 = (u32)f2bf(bf2f_lo(w.x) + ra.x) | ((u32)f2bf(bf2f_hi(w.x) + ra.y) << 16);
        u32 w1 = (u32)f2bf(bf2f_lo(w.y) + ra.z) | ((u32)f2bf(bf2f_hi(w.y) + ra.w) << 16);
        u32 w2 = (u32)f2bf(bf2f_lo(w.z) + rb.x) | ((u32)f2bf(bf2f_hi(w.z) + rb.y) << 16);
        u32 w3 = (u32)f2bf(bf2f_lo(w.w) + rb.z) | ((u32)f2bf(bf2f_hi(w.w) + rb.w) << 16);
        *(uint4*)((u16*)outp + gi) = make_uint4(w0, w1, w2, w3);
      } else {
        *(uint4*)((u16*)outp + gi) = w;
      }
    }
  }
}

// ---------- MFMA windowed attention: one wave per (window, head) ----------
// QKV interleaved bf16 (M, 1536): [Q 512 | K 512 | V 512]; out (M,512) bf16.
// 4 waves/block (4 heads of one window). 49 padded to 64 via row-clamp;
// padding columns masked to -1e30 in relL (baked by relprep_k) -> P == 0.
// Fragment conventions (verified by gemm_bt): A-frag row=l16, k=quad*8;
// B-frag "row" = output col; C/D col=lane&15, row=(lane>>4)*4+reg.
__global__ __launch_bounds__(256, 3)
void attn_k(const u16* __restrict__ QKV, const float* __restrict__ relL,
            u16* __restrict__ O) {
  __shared__ __align__(16) u16 Vt[4][32][PSTR];    // V^T per wave
  __shared__ __align__(16) u16 Pl[4][49 * PSTR];   // P, then O bounce

  const int tid  = threadIdx.x;
  const int wave = tid >> 6;
  const int lane = tid & 63;
  const int quad = lane >> 4;
  const int l16  = lane & 15;

  const int win  = blockIdx.x >> 2;                // 0..1023
  const int head = ((blockIdx.x & 3) << 2) + wave; // 0..15
  const int b    = win >> 6;
  const int wh   = (win >> 3) & 7;
  const int ww   = win & 7;
  const int base_l = b * Ll + (wh * 7) * Ww + ww * 7;

  // ---- stage V^T into LDS (all 64 lanes; pad rows k>=49 zeroed) ----
  u32 vw[16];
  #pragma unroll
  for (int i = 0; i < 16; i++) vw[i] = 0;
  const int lc = lane < 49 ? lane : 48;
  const size_t grl = (size_t)base_l + (lc / 7) * 56 + (lc % 7);
  if (lane < 49) {
    const uint4* vp = (const uint4*)(QKV + grl * 1536 + 1024 + head * HDd);
    uint4 a0 = vp[0], a1 = vp[1], a2 = vp[2], a3 = vp[3];
    vw[0]=a0.x;  vw[1]=a0.y;  vw[2]=a0.z;  vw[3]=a0.w;
    vw[4]=a1.x;  vw[5]=a1.y;  vw[6]=a1.z;  vw[7]=a1.w;
    vw[8]=a2.x;  vw[9]=a2.y;  vw[10]=a2.z; vw[11]=a2.w;
    vw[12]=a3.x; vw[13]=a3.y; vw[14]=a3.z; vw[15]=a3.w;
  }
  {
    u16* vtb = &Vt[wave][0][lane];
    #pragma unroll
    for (int c = 0; c < 32; c++)
      vtb[c * PSTR] = (u16)(vw[c >> 1] >> ((c & 1) << 4));
  }

  // ---- Q/K fragments direct from global (row-clamped) ----
  size_t gr16[4];
  #pragma unroll
  for (int t = 0; t < 4; t++) {
    int r = t * 16 + l16; if (r > 48) r = 48;
    gr16[t] = (size_t)base_l + (r / 7) * 56 + (r % 7);
  }
  short8 qf[4], kf[4];
  #pragma unroll
  for (int t = 0; t < 4; t++) {
    qf[t] = *(const short8*)(QKV + gr16[t] * 1536 + head * HDd + quad * 8);
    kf[t] = *(const short8*)(QKV + gr16[t] * 1536 + 512 + head * HDd + quad * 8);
  }

  // ---- QK^T: 16 MFMA ----
  floatx4 acc[4][4];
  #pragma unroll
  for (int mi = 0; mi < 4; mi++)
    #pragma unroll
    for (int nj = 0; nj < 4; nj++) acc[mi][nj] = (floatx4)0.f;
  #pragma unroll
  for (int mi = 0; mi < 4; mi++)
    #pragma unroll
    for (int nj = 0; nj < 4; nj++)
      acc[mi][nj] = __builtin_amdgcn_mfma_f32_16x16x32_bf16(
          qf[mi], kf[nj], acc[mi][nj], 0, 0, 0);

  // ---- scale + rel bias (mask baked in) ----
  const float* rlb = relL + ((size_t)head << 12) + lane * 4;
  #pragma unroll
  for (int mi = 0; mi < 4; mi++)
    #pragma unroll
    for (int nj = 0; nj < 4; nj++) {
      float4 rl = *(const float4*)(rlb + ((mi * 4 + nj) << 8));
      acc[mi][nj][0] = fmaf(acc[mi][nj][0], SCALE, rl.x);
      acc[mi][nj][1] = fmaf(acc[mi][nj][1], SCALE, rl.y);
      acc[mi][nj][2] = fmaf(acc[mi][nj][2], SCALE, rl.z);
      acc[mi][nj][3] = fmaf(acc[mi][nj][3], SCALE, rl.w);
    }

  // ---- row softmax (rows live in 16-lane groups; xor 1,2,4,8) ----
  float sums[4][4];
  #pragma unroll
  for (int mi = 0; mi < 4; mi++)
    #pragma unroll
    for (int r = 0; r < 4; r++) {
      float mx = fmaxf(fmaxf(acc[mi][0][r], acc[mi][1][r]),
                       fmaxf(acc[mi][2][r], acc[mi][3][r]));
      #pragma unroll
      for (int off = 8; off >= 1; off >>= 1)
        mx = fmaxf(mx, __shfl_xor(mx, off));
      float sm = 0.f;
      #pragma unroll
      for (int nj = 0; nj < 4; nj++) {
        float e = __expf(acc[mi][nj][r] - mx);
        acc[mi][nj][r] = e;
        sm += e;
      }
      #pragma unroll
      for (int off = 8; off >= 1; off >>= 1)
        sm += __shfl_xor(sm, off);
      sums[mi][r] = sm;
    }

  // ---- P -> bf16 -> LDS (rows<49; row 48 only from mi=3,quad=0,r=0) ----
  u16* Pw = Pl[wave];
  {
    u16* pb = Pw + (quad * 4) * PSTR + l16;
    #pragma unroll
    for (int mi = 0; mi < 3; mi++)
      #pragma unroll
      for (int r = 0; r < 4; r++)
        #pragma unroll
        for (int nj = 0; nj < 4; nj++)
          pb[(mi * 16 + r) * PSTR + nj * 16] = f2bf(acc[mi][nj][r]);
    if (quad == 0) {
      #pragma unroll
      for (int nj = 0; nj < 4; nj++)
        pb[48 * PSTR + nj * 16] = f2bf(acc[3][nj][0]);
    }
  }
  asm volatile("s_waitcnt lgkmcnt(0)" ::: "memory");

  // ---- PV: 16 MFMA (A = P rows, B = V cols via Vt) ----
  floatx4 pv[4][2];
  #pragma unroll
  for (int mi = 0; mi < 4; mi++)
    #pragma unroll
    for (int nj = 0; nj < 2; nj++) pv[mi][nj] = (floatx4)0.f;
  #pragma unroll
  for (int ks = 0; ks < 2; ks++) {
    short8 pf[4], vf[2];
    #pragma unroll
    for (int mi = 0; mi < 4; mi++) {
      const int pr = (mi < 3) ? (mi * 16 + l16) : 48;
      pf[mi] = *(const short8*)&Pw[pr * PSTR + ks * 32 + quad * 8];
    }
    #pragma unroll
    for (int nj = 0; nj < 2; nj++)
      vf[nj] = *(const short8*)&Vt[wave][nj * 16 + l16][ks * 32 + quad * 8];
    #pragma unroll
    for (int mi = 0; mi < 4; mi++)
      #pragma unroll
      for (int nj = 0; nj < 2; nj++)
        pv[mi][nj] = __builtin_amdgcn_mfma_f32_16x16x32_bf16(
            pf[mi], vf[nj], pv[mi][nj], 0, 0, 0);
  }

  // ---- O = pv/sum -> LDS bounce (reuse P buffer) -> coalesced store ----
  asm volatile("s_waitcnt lgkmcnt(0)" ::: "memory");
  {
    u16* ob = Pw + (quad * 4) * PSTR + l16;
    #pragma unroll
    for (int mi = 0; mi < 3; mi++)
      #pragma unroll
      for (int r = 0; r < 4; r++) {
        const float inv = __builtin_amdgcn_rcpf(sums[mi][r]);
        ob[(mi * 16 + r) * PSTR +  0] = f2bf(pv[mi][0][r] * inv);
        ob[(mi * 16 + r) * PSTR + 16] = f2bf(pv[mi][1][r] * inv);
      }
    if (quad == 0) {
      const float inv = __builtin_amdgcn_rcpf(sums[3][0]);
      ob[48 * PSTR +  0] = f2bf(pv[3][0][0] * inv);
      ob[48 * PSTR + 16] = f2bf(pv[3][1][0] * inv);
    }
  }
  asm volatile("s_waitcnt lgkmcnt(0)" ::: "memory");
  if (lane < 49) {
    const uint4* orow = (const uint4*)&Pw[lane * PSTR];
    uint4* op = (uint4*)(O + grl * 512 + head * HDd);
    op[0] = orow[0]; op[1] = orow[1]; op[2] = orow[2]; op[3] = orow[3];
  }
}

// ---------- launch ----------
extern "C" void kernel_launch(void* const* d_in, const int* in_sizes, int n_in,
                              void* d_out, int out_size, void* d_ws, size_t ws_size,
                              hipStream_t stream) {
  (void)in_sizes; (void)n_in; (void)out_size; (void)ws_size;
  const float* x    = (const float*)d_in[0];
  const float* Wq   = (const float*)d_in[1];
  const float* bq   = (const float*)d_in[2];
  const float* Wk   = (const float*)d_in[3];
  const float* bk   = (const float*)d_in[4];
  const float* Wv   = (const float*)d_in[5];
  const float* bv   = (const float*)d_in[6];
  const float* Wp   = (const float*)d_in[7];
  const float* bp   = (const float*)d_in[8];
  const float* rel  = (const float*)d_in[9];
  const float* g1   = (const float*)d_in[10];
  const float* b1   = (const float*)d_in[11];
  const float* g2   = (const float*)d_in[12];
  const float* b2   = (const float*)d_in[13];
  const float* W1   = (const float*)d_in[14];
  const float* bfc1 = (const float*)d_in[15];
  const float* W2   = (const float*)d_in[16];
  const float* bfc2 = (const float*)d_in[17];
  float* out = (float*)d_out;

  // workspace layout (u16 units)
  u16* wQKV = (u16*)d_ws;                          // 1536*512
  u16* wWp  = wQKV + (size_t)1536*512;             // 512*512
  u16* wW1  = wWp  + (size_t)512*512;              // 2048*512
  u16* wW2  = wW1  + (size_t)2048*512;             // 512*2048
  float* bqkv = (float*)(wW2 + (size_t)512*2048);  // 1536 fp32
  float* relL = bqkv + 1536;                       // 65536 fp32 (256 KB)
  u16* hbuf = (u16*)(relL + 65536);                // M*512 (LN1 out; later LN2 out)
  u16* QKVb = hbuf + (size_t)Mm * Cc;              // M*1536 (later: MLP hidden part)
  u16* Obuf = QKVb + (size_t)Mm * 1536;            // M*512
  u16* x2bf = Obuf + (size_t)Mm * Cc;              // M*512 bf16 residual
  u16* hid  = QKVb;                                // M*2048 overlays QKVb+Obuf
  u16* h2   = hbuf;

  // weights -> bf16 transposed (QKV fused into 1536 rows)
  wcvt_k<<<(512*512)/256,  256, 0, stream>>>(Wq, wQKV,              512, 512);
  wcvt_k<<<(512*512)/256,  256, 0, stream>>>(Wk, wQKV + 512*512,    512, 512);
  wcvt_k<<<(512*512)/256,  256, 0, stream>>>(Wv, wQKV + 2*512*512,  512, 512);
  wcvt_k<<<(512*512)/256,  256, 0, stream>>>(Wp, wWp, 512, 512);
  wcvt_k<<<(512*2048)/256, 256, 0, stream>>>(W1, wW1, 512, 2048);
  wcvt_k<<<(512*2048)/256, 256, 0, stream>>>(W2, wW2, 2048, 512);
  bcat_k<<<6, 256, 0, stream>>>(bq, bk, bv, bqkv);
  relprep_k<<<65536/256, 256, 0, stream>>>(rel, relL);

  // LN1
  ln_k<<<Mm/4, 256, 0, stream>>>(x, g1, b1, hbuf);

  // fused QKV projection: (M,1536), 392*12 blocks
  gemm_bt<0><<<392*12, 256, 0, stream>>>(hbuf, wQKV, bqkv, nullptr, QKVb,
                                         Mm, 1536, 512, 12);

  // attention (MFMA): 4096 blocks x 256 threads, 4 window-heads/block
  attn_k<<<4096, 256, 0, stream>>>(QKVb, relL, Obuf);

  // proj + residual(x fp32) -> x2 bf16
  gemm_bt<2><<<392*4, 256, 0, stream>>>(Obuf, wWp, bp, x, x2bf,
                                        Mm, 512, 512, 4);

  // LN2 (bf16 in)
  ln_bf_k<<<Mm/4, 256, 0, stream>>>(x2bf, g2, b2, h2);

  // MLP
  gemm_bt<1><<<392*16, 256, 0, stream>>>(h2, wW1, bfc1, nullptr, hid,
                                         Mm, 2048, 512, 16);
  gemm_bt<3><<<392*4, 256, 0, stream>>>(hid, wW2, bfc2, x2bf, out,
                                        Mm, 512, 2048, 4);
}